// Round 3
// baseline (244.534 us; speedup 1.0000x reference)
//
#include <hip/hip_runtime.h>

#define NB  32
#define NTC 2048
#define NTQ 256
#define ND  256

// ws layout (floats):
// m[32][2048] @0 ; h_part[32][16][256] @65536 ; h[32][256] @196608 ;
// q2[32][256] @204800 ; Qbf(bf16)[32][256][256] @212992f ; Qt(bf16)[32][256][256] @+1M floats
#define M_OFF   0
#define HP_OFF  65536
#define H_OFF   196608
#define Q2_OFF  204800
#define QBF_OFF 212992   // in floats; 4MB region
#define QT_OFF  (212992 + 1048576)

typedef __attribute__((ext_vector_type(8))) short short8v;
typedef __attribute__((ext_vector_type(4))) short short4v;
typedef __attribute__((ext_vector_type(4))) float float4v;

static __device__ inline short f2bf(float f) {
  union { float f; unsigned u; } v; v.f = f;
  unsigned r = v.u + 0x7FFFu + ((v.u >> 16) & 1u);
  return (short)(r >> 16);
}

// K0: per (b, 32-row q-chunk): Qbf = bf16(Q) row-major; Qt = bf16(Q)^T; q2 = Q.w2
__global__ __launch_bounds__(256) void k0_prep(const float* __restrict__ qry,
                                               const float* __restrict__ w,
                                               float* __restrict__ q2_ws,
                                               short* __restrict__ Qbf,
                                               short* __restrict__ Qt) {
  __shared__ float sRed[8][32];
  const int tid = threadIdx.x;
  const int b = blockIdx.x >> 3;
  const int q0 = (blockIdx.x & 7) << 5;
  const int q = tid & 31;        // local q row
  const int dc = tid >> 5;       // d-chunk of 32
  const float* src = qry + (((size_t)b * NTQ) + q0 + q) * ND + dc * 32;
  const float* w2p = w + ND + dc * 32;

  float vals[32];
  float part = 0.f;
  #pragma unroll
  for (int i = 0; i < 8; ++i) {
    float4 v = *(const float4*)(src + 4 * i);
    float4 u = *(const float4*)(w2p + 4 * i);
    part += v.x*u.x + v.y*u.y + v.z*u.z + v.w*u.w;
    vals[4*i] = v.x; vals[4*i+1] = v.y; vals[4*i+2] = v.z; vals[4*i+3] = v.w;
  }
  short pk[32];
  #pragma unroll
  for (int i = 0; i < 32; ++i) pk[i] = f2bf(vals[i]);

  // Qbf row-major
  short* dst = Qbf + ((size_t)b * NTQ + q0 + q) * ND + dc * 32;
  #pragma unroll
  for (int i = 0; i < 4; ++i) *(short8v*)(dst + 8 * i) = *(short8v*)(pk + 8 * i);
  // Qt transposed (scalar b16 stores, coalesced across q within half-wave)
  short* dstT = Qt + (size_t)b * NTQ * ND + q0 + q;
  #pragma unroll
  for (int i = 0; i < 32; ++i) dstT[(size_t)(dc * 32 + i) * NTQ] = pk[i];

  // q2 reduction: pairs (dc, dc^1) within wave, then LDS across waves
  part += __shfl_xor(part, 32);
  if ((tid & 32) == 0) sRed[dc][q] = part;
  __syncthreads();
  if (tid < 32) {
    float s = sRed[0][tid] + sRed[2][tid] + sRed[4][tid] + sRed[6][tid];
    q2_ws[b * NTQ + q0 + tid] = s;
  }
}

// K1: per (b, 64-row tile), BARRIER-FREE (per-wave LDS only).
// Phase1: S = s1 + q2 + (C*w3)Q^T (MFMA, B direct from Qbf). softmax in-reg.
// Phase2: U = P Q (MFMA, A from per-wave P^T LDS, B direct from Qt).
// Epilogue via per-wave LDS transpose -> float4 stores of U and C*U.
__global__ __launch_bounds__(256) void k1_main(const float* __restrict__ ctx,
                                               const float* __restrict__ w,
                                               const short* __restrict__ Qbf,
                                               const short* __restrict__ Qt,
                                               const float* __restrict__ q2_ws,
                                               float* __restrict__ m_ws,
                                               float* __restrict__ G) {
  __shared__ __align__(16) char smem[49152];  // sC 8KB (4x2KB) | sPT 40KB (4x10240B)

  const int tid  = threadIdx.x;
  const int wv   = tid >> 6;
  const int lane = tid & 63;
  const int g    = lane >> 4;
  const int li   = lane & 15;
  const int b    = blockIdx.x >> 5;
  const int t0   = (blockIdx.x & 31) << 6;

  short* sCw  = (short*)smem + wv * 1024;            // [16 rows][64 d] swizzled 16B slots
  short* sPTw = (short*)(smem + 8192) + wv * 5120;   // [256 q][20] P^T
  float* sUw  = (float*)sPTw;                        // [16][132] fp32 (reuse)

  const float* __restrict__ ctxB = ctx + ((size_t)b * NTC + t0) * ND;
  const short* __restrict__ Qb  = Qbf + (size_t)b * NTQ * ND;
  const short* __restrict__ Qtb = Qt  + (size_t)b * NTQ * ND;
  const float* w1 = w;
  const float* w3 = w + 2 * ND;

  float4v acc[16];
  #pragma unroll
  for (int n = 0; n < 16; ++n) acc[n] = (float4v)0.f;
  float s1part = 0.f;

  // ================= Phase 1 =================
  for (int dc = 0; dc < ND; dc += 64) {
    { // stage own wave's 16 C rows: lane (g,li) covers row li, cols 16g..16g+15
      const float* src = ctxB + (size_t)(16 * wv + li) * ND + dc + 16 * g;
      const float* w1p = w1 + dc + 16 * g;
      const float* w3p = w3 + dc + 16 * g;
      short8v pkLo, pkHi;
      #pragma unroll
      for (int jj = 0; jj < 2; ++jj) {
        float4 c0 = *(const float4*)(src + 8 * jj);
        float4 c1 = *(const float4*)(src + 8 * jj + 4);
        float4 a0 = *(const float4*)(w1p + 8 * jj);
        float4 a1 = *(const float4*)(w1p + 8 * jj + 4);
        float4 b0 = *(const float4*)(w3p + 8 * jj);
        float4 b1 = *(const float4*)(w3p + 8 * jj + 4);
        s1part += c0.x*a0.x + c0.y*a0.y + c0.z*a0.z + c0.w*a0.w
                + c1.x*a1.x + c1.y*a1.y + c1.z*a1.z + c1.w*a1.w;
        short8v pkv;
        pkv[0]=f2bf(c0.x*b0.x); pkv[1]=f2bf(c0.y*b0.y); pkv[2]=f2bf(c0.z*b0.z); pkv[3]=f2bf(c0.w*b0.w);
        pkv[4]=f2bf(c1.x*b1.x); pkv[5]=f2bf(c1.y*b1.y); pkv[6]=f2bf(c1.z*b1.z); pkv[7]=f2bf(c1.w*b1.w);
        if (jj == 0) pkLo = pkv; else pkHi = pkv;
      }
      *(short8v*)(sCw + li * 64 + (((2 * g)     ^ (li & 7)) << 3)) = pkLo;
      *(short8v*)(sCw + li * 64 + (((2 * g + 1) ^ (li & 7)) << 3)) = pkHi;
    }
    #pragma unroll
    for (int ks = 0; ks < 2; ++ks) {
      short8v a = *(short8v*)(sCw + li * 64 + (((4 * ks + g) ^ (li & 7)) << 3));
      #pragma unroll
      for (int n = 0; n < 16; ++n) {
        short8v bb = *(const short8v*)(Qb + (size_t)(16 * n + li) * ND + dc + 32 * ks + 8 * g);
        acc[n] = __builtin_amdgcn_mfma_f32_16x16x32_bf16(a, bb, acc[n], 0, 0, 0);
      }
    }
  }

  // ================= softmax (rows 16wv+4g+r, cols 16n+li) =================
  s1part += __shfl_xor(s1part, 16);
  s1part += __shfl_xor(s1part, 32);
  float s1r[4];
  #pragma unroll
  for (int r = 0; r < 4; ++r) s1r[r] = __shfl(s1part, 4 * g + r);

  float q2v[16];
  #pragma unroll
  for (int n = 0; n < 16; ++n) q2v[n] = q2_ws[b * NTQ + 16 * n + li];

  #pragma unroll
  for (int n = 0; n < 16; ++n)
    #pragma unroll
    for (int r = 0; r < 4; ++r) acc[n][r] += s1r[r] + q2v[n];

  float mx[4], inv[4];
  #pragma unroll
  for (int r = 0; r < 4; ++r) {
    float m0 = acc[0][r];
    #pragma unroll
    for (int n = 1; n < 16; ++n) m0 = fmaxf(m0, acc[n][r]);
    m0 = fmaxf(m0, __shfl_xor(m0, 1));
    m0 = fmaxf(m0, __shfl_xor(m0, 2));
    m0 = fmaxf(m0, __shfl_xor(m0, 4));
    m0 = fmaxf(m0, __shfl_xor(m0, 8));
    mx[r] = m0;
  }
  if (li == 0) {
    #pragma unroll
    for (int r = 0; r < 4; ++r) m_ws[b * NTC + t0 + 16 * wv + 4 * g + r] = mx[r];
  }
  #pragma unroll
  for (int r = 0; r < 4; ++r) {
    float z = 0.f;
    #pragma unroll
    for (int n = 0; n < 16; ++n) { float e = __expf(acc[n][r] - mx[r]); acc[n][r] = e; z += e; }
    z += __shfl_xor(z, 1);
    z += __shfl_xor(z, 2);
    z += __shfl_xor(z, 4);
    z += __shfl_xor(z, 8);
    inv[r] = 1.0f / z;
  }
  #pragma unroll
  for (int n = 0; n < 16; ++n) {
    short4v pk;
    #pragma unroll
    for (int r = 0; r < 4; ++r) pk[r] = f2bf(acc[n][r] * inv[r]);
    *(short4v*)(sPTw + (16 * n + li) * 20 + 4 * g) = pk;   // P^T[q][t-local]
  }

  // ================= Phase 2: U = P @ Q =================
  float4v acc2[16];
  #pragma unroll
  for (int n = 0; n < 16; ++n) acc2[n] = (float4v)0.f;

  for (int qc = 0; qc < 4; ++qc) {
    #pragma unroll
    for (int kl = 0; kl < 2; ++kl) {
      short8v a2;
      #pragma unroll
      for (int e = 0; e < 8; ++e)
        a2[e] = sPTw[(qc * 64 + 32 * kl + 8 * g + e) * 20 + li];
      #pragma unroll
      for (int n = 0; n < 16; ++n) {
        short8v b2 = *(const short8v*)(Qtb + (size_t)(16 * n + li) * NTQ + qc * 64 + 32 * kl + 8 * g);
        acc2[n] = __builtin_amdgcn_mfma_f32_16x16x32_bf16(a2, b2, acc2[n], 0, 0, 0);
      }
    }
  }

  // ================= epilogue: per-wave LDS transpose, float4 stores =================
  const int te = lane >> 2;            // row 0..15
  const int ce = (lane & 3) * 32;      // col base within 128-half
  #pragma unroll
  for (int h = 0; h < 2; ++h) {
    #pragma unroll
    for (int nn = 0; nn < 8; ++nn) {
      const int n = 8 * h + nn;
      #pragma unroll
      for (int r = 0; r < 4; ++r)
        sUw[(4 * g + r) * 132 + 16 * nn + li] = acc2[n][r];
    }
    __builtin_amdgcn_s_waitcnt(0);  // lgkm drain for own-wave ds writes (cheap, wave-local)
    #pragma unroll
    for (int i = 0; i < 8; ++i) {
      float4 u = *(const float4*)(sUw + te * 132 + ce + 4 * i);
      const float* cp = ctxB + (size_t)(16 * wv + te) * ND + 128 * h + ce + 4 * i;
      float4 c = *(const float4*)cp;
      const size_t gb = ((size_t)b * NTC + t0 + 16 * wv + te) * 1024 + 128 * h + ce + 4 * i;
      *(float4*)(G + gb + 256) = u;
      *(float4*)(G + gb + 512) = make_float4(c.x*u.x, c.y*u.y, c.z*u.z, c.w*u.w);
    }
    __builtin_amdgcn_s_waitcnt(0);  // reads done before next-half overwrite
  }
}

// K2: per (b, t-slice of 128): batch softmax over t of m, partial h
__global__ __launch_bounds__(256) void k2_bt(const float* __restrict__ ctx,
                                             const float* __restrict__ m_ws,
                                             float* __restrict__ h_part) {
  __shared__ __align__(16) float sM[NTC];
  __shared__ float red[32];
  int b = blockIdx.x >> 4;
  int slice = blockIdx.x & 15;
  int tid = threadIdx.x;

  float lm = -1e30f;
  #pragma unroll
  for (int k = 0; k < 8; ++k) {
    float v = m_ws[b * NTC + tid * 8 + k];
    sM[tid * 8 + k] = v;
    lm = fmaxf(lm, v);
  }
  #pragma unroll
  for (int s = 1; s < 64; s <<= 1) lm = fmaxf(lm, __shfl_xor(lm, s));
  if ((tid & 63) == 0) red[tid >> 6] = lm;
  __syncthreads();
  float M = fmaxf(fmaxf(red[0], red[1]), fmaxf(red[2], red[3]));
  float ls = 0.f;
  #pragma unroll
  for (int k = 0; k < 8; ++k) ls += __expf(sM[tid * 8 + k] - M);
  #pragma unroll
  for (int s = 1; s < 64; s <<= 1) ls += __shfl_xor(ls, s);
  if ((tid & 63) == 0) red[16 + (tid >> 6)] = ls;
  __syncthreads();
  float invZ = 1.0f / (red[16] + red[17] + red[18] + red[19]);

  int tbase = slice * 128;
  const float* cb = ctx + ((size_t)b * NTC + tbase) * ND + tid;
  float acc = 0.f;
  #pragma unroll 8
  for (int t = 0; t < 128; ++t) {
    float btv = __expf(sM[tbase + t] - M) * invZ;
    acc += btv * cb[(size_t)t * ND];
  }
  h_part[((size_t)b * 16 + slice) * ND + tid] = acc;
}

__global__ __launch_bounds__(256) void k2b_hred(const float* __restrict__ h_part,
                                                float* __restrict__ h_ws) {
  int b = blockIdx.x;
  int d = threadIdx.x;
  float acc = 0.f;
  #pragma unroll
  for (int s = 0; s < 16; ++s) acc += h_part[((size_t)b * 16 + s) * ND + d];
  h_ws[b * ND + d] = acc;
}

// K3: G[...,0:256] = C ; G[...,768:1024] = C * h[b,:]
__global__ __launch_bounds__(256) void k3_epi(const float* __restrict__ ctx,
                                              const float* __restrict__ h_ws,
                                              float* __restrict__ G) {
  size_t f = (size_t)blockIdx.x * 256 + threadIdx.x;
  size_t e = f * 4;
  int d = (int)(e & 255);
  size_t bt = e >> 8;
  int b = (int)(bt >> 11);
  float4 c = *(const float4*)(ctx + e);
  float4 h = *(const float4*)(h_ws + b * ND + d);
  *(float4*)(G + bt * 1024 + d) = c;
  *(float4*)(G + bt * 1024 + 768 + d) =
      make_float4(c.x * h.x, c.y * h.y, c.z * h.z, c.w * h.w);
}

extern "C" void kernel_launch(void* const* d_in, const int* in_sizes, int n_in,
                              void* d_out, int out_size, void* d_ws, size_t ws_size,
                              hipStream_t stream) {
  const float* ctx = (const float*)d_in[0];
  const float* qry = (const float*)d_in[1];
  const float* w   = (const float*)d_in[2];
  float* G  = (float*)d_out;
  float* ws = (float*)d_ws;
  float* m_ws   = ws + M_OFF;
  float* h_part = ws + HP_OFF;
  float* h_ws   = ws + H_OFF;
  float* q2_ws  = ws + Q2_OFF;
  short* Qbf = (short*)(ws + QBF_OFF);
  short* Qt  = (short*)(ws + QT_OFF);

  k0_prep<<<NB * 8, 256, 0, stream>>>(qry, w, q2_ws, Qbf, Qt);
  k1_main<<<NB * (NTC / 64), 256, 0, stream>>>(ctx, w, Qbf, Qt, q2_ws, m_ws, G);
  k2_bt<<<NB * 16, 256, 0, stream>>>(ctx, m_ws, h_part);
  k2b_hred<<<NB, 256, 0, stream>>>(h_part, h_ws);
  k3_epi<<<16384, 256, 0, stream>>>(ctx, h_ws, G);
}

// Round 4
// 208.231 us; speedup vs baseline: 1.1743x; 1.1743x over previous
//
#include <hip/hip_runtime.h>

#define NB  32
#define NTC 2048
#define NTQ 256
#define ND  256

// ws layout (floats):
// m[32][2048] @0 ; h_part[32][16][256] @65536 ; h[32][256] @196608 ;
// q2[32][256] @204800 ; Qbf(bf16)[32][256][256] @212992f ; Qt(bf16) @+1M floats
#define M_OFF   0
#define HP_OFF  65536
#define H_OFF   196608
#define Q2_OFF  204800
#define QBF_OFF 212992
#define QT_OFF  (212992 + 1048576)

#define PSTR 264   // sP row stride (shorts): 528B = 16B-aligned, even bank spread
#define USTR 130   // sU row stride (floats)

typedef __attribute__((ext_vector_type(8))) short short8v;
typedef __attribute__((ext_vector_type(4))) float float4v;

static __device__ inline short f2bf(float f) {
  union { float f; unsigned u; } v; v.f = f;
  unsigned r = v.u + 0x7FFFu + ((v.u >> 16) & 1u);
  return (short)(r >> 16);
}

// K0: per (b, 32-row q-chunk): Qbf = bf16(Q) row-major; Qt = bf16(Q)^T; q2 = Q.w2
__global__ __launch_bounds__(256) void k0_prep(const float* __restrict__ qry,
                                               const float* __restrict__ w,
                                               float* __restrict__ q2_ws,
                                               short* __restrict__ Qbf,
                                               short* __restrict__ Qt) {
  __shared__ float sRed[8][32];
  const int tid = threadIdx.x;
  const int b = blockIdx.x >> 3;
  const int q0 = (blockIdx.x & 7) << 5;
  const int q = tid & 31;
  const int dc = tid >> 5;
  const float* src = qry + (((size_t)b * NTQ) + q0 + q) * ND + dc * 32;
  const float* w2p = w + ND + dc * 32;

  float vals[32];
  float part = 0.f;
  #pragma unroll
  for (int i = 0; i < 8; ++i) {
    float4 v = *(const float4*)(src + 4 * i);
    float4 u = *(const float4*)(w2p + 4 * i);
    part += v.x*u.x + v.y*u.y + v.z*u.z + v.w*u.w;
    vals[4*i] = v.x; vals[4*i+1] = v.y; vals[4*i+2] = v.z; vals[4*i+3] = v.w;
  }
  short pk[32];
  #pragma unroll
  for (int i = 0; i < 32; ++i) pk[i] = f2bf(vals[i]);

  short* dst = Qbf + ((size_t)b * NTQ + q0 + q) * ND + dc * 32;
  #pragma unroll
  for (int i = 0; i < 4; ++i) *(short8v*)(dst + 8 * i) = *(short8v*)(pk + 8 * i);
  short* dstT = Qt + (size_t)b * NTQ * ND + q0 + q;
  #pragma unroll
  for (int i = 0; i < 32; ++i) dstT[(size_t)(dc * 32 + i) * NTQ] = pk[i];

  part += __shfl_xor(part, 32);
  if ((tid & 32) == 0) sRed[dc][q] = part;
  __syncthreads();
  if (tid < 32) {
    float s = sRed[0][tid] + sRed[2][tid] + sRed[4][tid] + sRed[6][tid];
    q2_ws[b * NTQ + q0 + tid] = s;
  }
}

// K1: per (b, 64-row tile). Barrier-free, per-wave LDS only.
// Phase1: S = s1 + q2 + (C*w3)Q^T (MFMA, B rotate-prefetched from Qbf global).
// Softmax in-register. P row-major per-wave LDS. Phase2: U = P Q (B from Qt).
// Epilogue: LDS transpose -> sector-aligned float4 stores of G0=C, G1=U, G2=C*U.
__global__ __launch_bounds__(256, 3) void k1_main(const float* __restrict__ ctx,
                                                  const float* __restrict__ w,
                                                  const short* __restrict__ Qbf,
                                                  const short* __restrict__ Qt,
                                                  const float* __restrict__ q2_ws,
                                                  float* __restrict__ m_ws,
                                                  float* __restrict__ G) {
  __shared__ __align__(16) short sC_all[4 * 16 * 64];    // 8KB: per-wave C*w3 frags
  __shared__ __align__(16) short sP_all[4 * 16 * PSTR];  // 33KB: per-wave P (sU overlay)

  const int tid  = threadIdx.x;
  const int wv   = tid >> 6;
  const int lane = tid & 63;
  const int g    = lane >> 4;
  const int li   = lane & 15;
  const int bid  = blockIdx.x;
  const int obid = (bid & 7) * 128 + (bid >> 3);   // XCD-bijective swizzle (1024 = 8*128)
  const int b    = obid >> 5;
  const int t0   = (obid & 31) << 6;

  short* sCw = sC_all + wv * (16 * 64);
  short* sPw = sP_all + wv * (16 * PSTR);
  float* sUw = (float*)sPw;

  const float* __restrict__ ctxB = ctx + ((size_t)b * NTC + t0) * ND;
  const short* __restrict__ Qb   = Qbf + (size_t)b * NTQ * ND;
  const short* __restrict__ Qtb  = Qt  + (size_t)b * NTQ * ND;
  const float* w1 = w;
  const float* w3 = w + 2 * ND;

  float4v acc[16];
  #pragma unroll
  for (int n = 0; n < 16; ++n) acc[n] = (float4v)0.f;
  float s1part = 0.f;

  // ---- Phase 1: rotate-pipelined MFMA, B direct from global Qbf ----
  short8v bf[16];
  #pragma unroll
  for (int n = 0; n < 16; ++n)
    bf[n] = *(const short8v*)(Qb + (size_t)(16 * n + li) * ND + 8 * g);

  short8v a0, a1;
  #pragma unroll
  for (int s = 0; s < 8; ++s) {
    const int dc = (s >> 1) << 6;
    if ((s & 1) == 0) {
      const float* src = ctxB + (size_t)(16 * wv + li) * ND + dc + 16 * g;
      const float* w1p = w1 + dc + 16 * g;
      const float* w3p = w3 + dc + 16 * g;
      #pragma unroll
      for (int jj = 0; jj < 2; ++jj) {
        float4 c0 = *(const float4*)(src + 8 * jj);
        float4 c1 = *(const float4*)(src + 8 * jj + 4);
        float4 wa0 = *(const float4*)(w1p + 8 * jj);
        float4 wa1 = *(const float4*)(w1p + 8 * jj + 4);
        float4 wb0 = *(const float4*)(w3p + 8 * jj);
        float4 wb1 = *(const float4*)(w3p + 8 * jj + 4);
        s1part += c0.x*wa0.x + c0.y*wa0.y + c0.z*wa0.z + c0.w*wa0.w
                + c1.x*wa1.x + c1.y*wa1.y + c1.z*wa1.z + c1.w*wa1.w;
        short8v pkv;
        pkv[0]=f2bf(c0.x*wb0.x); pkv[1]=f2bf(c0.y*wb0.y); pkv[2]=f2bf(c0.z*wb0.z); pkv[3]=f2bf(c0.w*wb0.w);
        pkv[4]=f2bf(c1.x*wb1.x); pkv[5]=f2bf(c1.y*wb1.y); pkv[6]=f2bf(c1.z*wb1.z); pkv[7]=f2bf(c1.w*wb1.w);
        *(short8v*)(sCw + li * 64 + (((2 * g + jj) ^ (li & 7)) << 3)) = pkv;
      }
      a0 = *(short8v*)(sCw + li * 64 + ((g       ^ (li & 7)) << 3));
      a1 = *(short8v*)(sCw + li * 64 + (((4 + g) ^ (li & 7)) << 3));
    }
    const short8v af = (s & 1) ? a1 : a0;
    const int ns = s + 1;
    const int noff = ((ns >> 1) << 6) + ((ns & 1) << 5) + 8 * g;
    #pragma unroll
    for (int n = 0; n < 16; ++n) {
      acc[n] = __builtin_amdgcn_mfma_f32_16x16x32_bf16(af, bf[n], acc[n], 0, 0, 0);
      if (s < 7)
        bf[n] = *(const short8v*)(Qb + (size_t)(16 * n + li) * ND + noff);
    }
  }

  // ---- softmax (rows 16wv+4g+r, cols 16n+li) ----
  s1part += __shfl_xor(s1part, 16);
  s1part += __shfl_xor(s1part, 32);
  float s1r[4];
  #pragma unroll
  for (int r = 0; r < 4; ++r) s1r[r] = __shfl(s1part, 4 * g + r);

  float q2v[16];
  #pragma unroll
  for (int n = 0; n < 16; ++n) q2v[n] = q2_ws[b * NTQ + 16 * n + li];

  #pragma unroll
  for (int n = 0; n < 16; ++n)
    #pragma unroll
    for (int r = 0; r < 4; ++r) acc[n][r] += s1r[r] + q2v[n];

  float mx[4], inv[4];
  #pragma unroll
  for (int r = 0; r < 4; ++r) {
    float m0 = acc[0][r];
    #pragma unroll
    for (int n = 1; n < 16; ++n) m0 = fmaxf(m0, acc[n][r]);
    m0 = fmaxf(m0, __shfl_xor(m0, 1));
    m0 = fmaxf(m0, __shfl_xor(m0, 2));
    m0 = fmaxf(m0, __shfl_xor(m0, 4));
    m0 = fmaxf(m0, __shfl_xor(m0, 8));
    mx[r] = m0;
  }
  if (li == 0) {
    #pragma unroll
    for (int r = 0; r < 4; ++r) m_ws[b * NTC + t0 + 16 * wv + 4 * g + r] = mx[r];
  }
  #pragma unroll
  for (int r = 0; r < 4; ++r) {
    float z = 0.f;
    #pragma unroll
    for (int n = 0; n < 16; ++n) { float e = __expf(acc[n][r] - mx[r]); acc[n][r] = e; z += e; }
    z += __shfl_xor(z, 1);
    z += __shfl_xor(z, 2);
    z += __shfl_xor(z, 4);
    z += __shfl_xor(z, 8);
    inv[r] = 1.0f / z;
  }

  // ---- P row-major into per-wave LDS ----
  #pragma unroll
  for (int n = 0; n < 16; ++n) {
    #pragma unroll
    for (int r = 0; r < 4; ++r)
      sPw[(4 * g + r) * PSTR + 16 * n + li] = f2bf(acc[n][r] * inv[r]);
  }

  // ---- Phase 2: U = P @ Q, rotate-pipelined, B direct from global Qt ----
  float4v acc2[16];
  #pragma unroll
  for (int n = 0; n < 16; ++n) acc2[n] = (float4v)0.f;

  short8v bf2[16];
  #pragma unroll
  for (int n = 0; n < 16; ++n)
    bf2[n] = *(const short8v*)(Qtb + (size_t)(16 * n + li) * NTQ + 8 * g);
  short8v a2c = *(const short8v*)(sPw + li * PSTR + 8 * g);

  #pragma unroll
  for (int s2 = 0; s2 < 8; ++s2) {
    const int ns = s2 + 1;
    const int noff = ((ns >> 1) << 6) + ((ns & 1) << 5) + 8 * g;
    short8v a2n = a2c;
    if (s2 < 7) a2n = *(const short8v*)(sPw + li * PSTR + noff);
    #pragma unroll
    for (int n = 0; n < 16; ++n) {
      acc2[n] = __builtin_amdgcn_mfma_f32_16x16x32_bf16(a2c, bf2[n], acc2[n], 0, 0, 0);
      if (s2 < 7)
        bf2[n] = *(const short8v*)(Qtb + (size_t)(16 * n + li) * NTQ + noff);
    }
    a2c = a2n;
  }

  // ---- epilogue: per-wave LDS transpose, sector-aligned stores ----
  asm volatile("s_waitcnt lgkmcnt(0)" ::: "memory");   // sP reads drained before overlay
  __builtin_amdgcn_sched_barrier(0);
  #pragma unroll
  for (int h = 0; h < 2; ++h) {
    #pragma unroll
    for (int nn = 0; nn < 8; ++nn) {
      const int n = 8 * h + nn;
      #pragma unroll
      for (int r = 0; r < 4; ++r)
        sUw[(4 * g + r) * USTR + 16 * nn + li] = acc2[n][r];
    }
    asm volatile("s_waitcnt lgkmcnt(0)" ::: "memory");
    __builtin_amdgcn_sched_barrier(0);
    #pragma unroll
    for (int r0 = 0; r0 < 16; r0 += 4) {
      const int row = r0 + g;
      #pragma unroll
      for (int j = 0; j < 2; ++j) {
        float4 u = *(const float4*)(sUw + row * USTR + 64 * j + 4 * li);
        const int gcol = 128 * h + 64 * j + 4 * li;
        const float* cp = ctxB + (size_t)(16 * wv + row) * ND + gcol;
        float4 c = *(const float4*)cp;
        const size_t gb = ((size_t)b * NTC + t0 + 16 * wv + row) * 1024 + gcol;
        *(float4*)(G + gb)       = c;                                            // G0 = C
        *(float4*)(G + gb + 256) = u;                                            // G1 = U
        *(float4*)(G + gb + 512) = make_float4(c.x*u.x, c.y*u.y, c.z*u.z, c.w*u.w); // G2
      }
    }
  }
}

// K2: per (b, t-slice of 128): batch softmax over t of m, partial h
__global__ __launch_bounds__(256) void k2_bt(const float* __restrict__ ctx,
                                             const float* __restrict__ m_ws,
                                             float* __restrict__ h_part) {
  __shared__ __align__(16) float sM[NTC];
  __shared__ float red[32];
  int b = blockIdx.x >> 4;
  int slice = blockIdx.x & 15;
  int tid = threadIdx.x;

  float lm = -1e30f;
  #pragma unroll
  for (int k = 0; k < 8; ++k) {
    float v = m_ws[b * NTC + tid * 8 + k];
    sM[tid * 8 + k] = v;
    lm = fmaxf(lm, v);
  }
  #pragma unroll
  for (int s = 1; s < 64; s <<= 1) lm = fmaxf(lm, __shfl_xor(lm, s));
  if ((tid & 63) == 0) red[tid >> 6] = lm;
  __syncthreads();
  float M = fmaxf(fmaxf(red[0], red[1]), fmaxf(red[2], red[3]));
  float ls = 0.f;
  #pragma unroll
  for (int k = 0; k < 8; ++k) ls += __expf(sM[tid * 8 + k] - M);
  #pragma unroll
  for (int s = 1; s < 64; s <<= 1) ls += __shfl_xor(ls, s);
  if ((tid & 63) == 0) red[16 + (tid >> 6)] = ls;
  __syncthreads();
  float invZ = 1.0f / (red[16] + red[17] + red[18] + red[19]);

  int tbase = slice * 128;
  const float* cb = ctx + ((size_t)b * NTC + tbase) * ND + tid;
  float acc = 0.f;
  #pragma unroll 8
  for (int t = 0; t < 128; ++t) {
    float btv = __expf(sM[tbase + t] - M) * invZ;
    acc += btv * cb[(size_t)t * ND];
  }
  h_part[((size_t)b * 16 + slice) * ND + tid] = acc;
}

__global__ __launch_bounds__(256) void k2b_hred(const float* __restrict__ h_part,
                                                float* __restrict__ h_ws) {
  int b = blockIdx.x;
  int d = threadIdx.x;
  float acc = 0.f;
  #pragma unroll
  for (int s = 0; s < 16; ++s) acc += h_part[((size_t)b * 16 + s) * ND + d];
  h_ws[b * ND + d] = acc;
}

// K3: G[...,768:1024] = C * h[b,:]   (G0 now written by k1)
__global__ __launch_bounds__(256) void k3_epi(const float* __restrict__ ctx,
                                              const float* __restrict__ h_ws,
                                              float* __restrict__ G) {
  size_t f = (size_t)blockIdx.x * 256 + threadIdx.x;
  size_t e = f * 4;
  int d = (int)(e & 255);
  size_t bt = e >> 8;
  int b = (int)(bt >> 11);
  float4 c = *(const float4*)(ctx + e);
  float4 h = *(const float4*)(h_ws + b * ND + d);
  *(float4*)(G + bt * 1024 + 768 + d) =
      make_float4(c.x * h.x, c.y * h.y, c.z * h.z, c.w * h.w);
}

extern "C" void kernel_launch(void* const* d_in, const int* in_sizes, int n_in,
                              void* d_out, int out_size, void* d_ws, size_t ws_size,
                              hipStream_t stream) {
  const float* ctx = (const float*)d_in[0];
  const float* qry = (const float*)d_in[1];
  const float* w   = (const float*)d_in[2];
  float* G  = (float*)d_out;
  float* ws = (float*)d_ws;
  float* m_ws   = ws + M_OFF;
  float* h_part = ws + HP_OFF;
  float* h_ws   = ws + H_OFF;
  float* q2_ws  = ws + Q2_OFF;
  short* Qbf = (short*)(ws + QBF_OFF);
  short* Qt  = (short*)(ws + QT_OFF);

  k0_prep<<<NB * 8, 256, 0, stream>>>(qry, w, q2_ws, Qbf, Qt);
  k1_main<<<NB * (NTC / 64), 256, 0, stream>>>(ctx, w, Qbf, Qt, q2_ws, m_ws, G);
  k2_bt<<<NB * 16, 256, 0, stream>>>(ctx, m_ws, h_part);
  k2b_hred<<<NB, 256, 0, stream>>>(h_part, h_ws);
  k3_epi<<<16384, 256, 0, stream>>>(ctx, h_ws, G);
}

// Round 5
// 120.481 us; speedup vs baseline: 2.0296x; 1.7283x over previous
//
#include <hip/hip_runtime.h>

#define NB  32
#define NTC 2048
#define NTQ 256
#define ND  256

// ws layout (floats):
// m[32][2048] @0 ; h_part[32][16][256] @65536 ; h[32][256] @196608 ;
// q2[32][256] @204800 ; Qbf(bf16)[32][256][256] @212992f ; Qt(bf16) @+1M floats
#define M_OFF   0
#define HP_OFF  65536
#define H_OFF   196608
#define Q2_OFF  204800
#define QBF_OFF 212992
#define QT_OFF  (212992 + 1048576)

#define PSTR 264   // sP row stride (shorts): 528B, 16B-aligned, odd 16B-block count
#define USTR 130   // sU row stride (floats)

typedef __attribute__((ext_vector_type(8))) short short8v;
typedef __attribute__((ext_vector_type(4))) float float4v;
typedef unsigned int u32;

static __device__ inline short f2bf(float f) {
  union { float f; unsigned u; } v; v.f = f;
  unsigned r = v.u + 0x7FFFu + ((v.u >> 16) & 1u);
  return (short)(r >> 16);
}

// async global->LDS, 16B per lane; LDS dest = wave-uniform base + lane*16
static __device__ inline void gload_lds16(const short* g, short* l) {
  __builtin_amdgcn_global_load_lds(
      (const __attribute__((address_space(1))) u32*)g,
      (__attribute__((address_space(3))) u32*)l, 16, 0, 0);
}

// K0: per (b, 32-row q-chunk): Qbf = bf16(Q) row-major; Qt = bf16(Q)^T; q2 = Q.w2
__global__ __launch_bounds__(256) void k0_prep(const float* __restrict__ qry,
                                               const float* __restrict__ w,
                                               float* __restrict__ q2_ws,
                                               short* __restrict__ Qbf,
                                               short* __restrict__ Qt) {
  __shared__ float sRed[8][32];
  const int tid = threadIdx.x;
  const int b = blockIdx.x >> 3;
  const int q0 = (blockIdx.x & 7) << 5;
  const int q = tid & 31;
  const int dc = tid >> 5;
  const float* src = qry + (((size_t)b * NTQ) + q0 + q) * ND + dc * 32;
  const float* w2p = w + ND + dc * 32;

  float vals[32];
  float part = 0.f;
  #pragma unroll
  for (int i = 0; i < 8; ++i) {
    float4 v = *(const float4*)(src + 4 * i);
    float4 u = *(const float4*)(w2p + 4 * i);
    part += v.x*u.x + v.y*u.y + v.z*u.z + v.w*u.w;
    vals[4*i] = v.x; vals[4*i+1] = v.y; vals[4*i+2] = v.z; vals[4*i+3] = v.w;
  }
  short pk[32];
  #pragma unroll
  for (int i = 0; i < 32; ++i) pk[i] = f2bf(vals[i]);

  short* dst = Qbf + ((size_t)b * NTQ + q0 + q) * ND + dc * 32;
  #pragma unroll
  for (int i = 0; i < 4; ++i) *(short8v*)(dst + 8 * i) = *(short8v*)(pk + 8 * i);
  short* dstT = Qt + (size_t)b * NTQ * ND + q0 + q;
  #pragma unroll
  for (int i = 0; i < 32; ++i) dstT[(size_t)(dc * 32 + i) * NTQ] = pk[i];

  part += __shfl_xor(part, 32);
  if ((tid & 32) == 0) sRed[dc][q] = part;
  __syncthreads();
  if (tid < 32) {
    float s = sRed[0][tid] + sRed[2][tid] + sRed[4][tid] + sRed[6][tid];
    q2_ws[b * NTQ + q0 + tid] = s;
  }
}

// K1: per (b, 64-row tile). T3-style double-buffered LDS staging of Q chunks.
// Phase1 (chunks 0..7): S = s1+q2+(C*w3)Q^T. Softmax in-reg -> sP (per-wave).
// Phase2 (chunks 8..15): U = P Q (B from staged Qt). Epilogue: G0=C,G1=U,G2=C*U.
__global__ __launch_bounds__(256, 2) void k1_main(const float* __restrict__ ctx,
                                                  const float* __restrict__ w,
                                                  const short* __restrict__ Qbf,
                                                  const short* __restrict__ Qt,
                                                  const float* __restrict__ q2_ws,
                                                  float* __restrict__ m_ws,
                                                  float* __restrict__ G) {
  __shared__ __align__(16) short sStage[2][256 * 32];    // 2 x 16KB
  __shared__ __align__(16) short sP_all[4 * 16 * PSTR];  // 33KB per-wave P / sU overlay

  const int tid  = threadIdx.x;
  const int wv   = tid >> 6;
  const int lane = tid & 63;
  const int g    = lane >> 4;
  const int li   = lane & 15;
  const int bid  = blockIdx.x;
  const int obid = (bid & 7) * 128 + (bid >> 3);   // XCD-bijective swizzle
  const int b    = obid >> 5;
  const int t0   = (obid & 31) << 6;

  short* sPw = sP_all + wv * (16 * PSTR);
  float* sUw = (float*)sPw;

  const float* __restrict__ ctxB = ctx + ((size_t)b * NTC + t0) * ND;
  const short* __restrict__ Qb   = Qbf + (size_t)b * NTQ * ND;
  const short* __restrict__ Qtb  = Qt  + (size_t)b * NTQ * ND;

  const int srow = 64 * wv + (lane >> 2);      // staging row base (per j: +16)
  const int sblk = lane & 3;

  // stage one 256x32 bf16 chunk into sStage[buf]; source pre-swizzled so that
  // LDS slot (row, blk) holds global granule blk ^ ((row>>1)&3)
  #define STAGE(buf, src, c0)                                                   \
    { _Pragma("unroll")                                                         \
      for (int j = 0; j < 4; ++j) {                                             \
        const int row_ = srow + 16 * j;                                         \
        const int gi_  = sblk ^ ((row_ >> 1) & 3);                              \
        gload_lds16((src) + (size_t)row_ * 256 + (c0) + 8 * gi_,                \
                    &sStage[buf][wv * 2048 + j * 512]);                         \
      } }

  float4v acc[16];
  #pragma unroll
  for (int n = 0; n < 16; ++n) acc[n] = (float4v)0.f;
  float s1part = 0.f;

  // ---- prologue: stage chunk 0, prefetch A(0) ----
  STAGE(0, Qb, 0);
  const float* arow = ctxB + (size_t)(16 * wv + li) * ND + 8 * g;
  float4 Ac0 = *(const float4*)(arow);
  float4 Ac1 = *(const float4*)(arow + 4);
  __syncthreads();

  // ---- Phase 1: chunks 0..7 (K=32 each) ----
  for (int c = 0; c < 8; ++c) {
    float4 An0, An1;
    if (c < 7) {
      STAGE((c + 1) & 1, Qb, 32 * (c + 1));
      An0 = *(const float4*)(arow + 32 * (c + 1));
      An1 = *(const float4*)(arow + 32 * (c + 1) + 4);
    } else {
      STAGE(0, Qtb, 0);   // phase-2 chunk 8 prefetch (buf 0)
    }
    const float* w1p = w + 32 * c + 8 * g;
    const float* w3p = w + 2 * ND + 32 * c + 8 * g;
    float4 u0 = *(const float4*)w1p, u1 = *(const float4*)(w1p + 4);
    float4 v0 = *(const float4*)w3p, v1 = *(const float4*)(w3p + 4);
    s1part += Ac0.x*u0.x + Ac0.y*u0.y + Ac0.z*u0.z + Ac0.w*u0.w
            + Ac1.x*u1.x + Ac1.y*u1.y + Ac1.z*u1.z + Ac1.w*u1.w;
    short8v af;
    af[0]=f2bf(Ac0.x*v0.x); af[1]=f2bf(Ac0.y*v0.y); af[2]=f2bf(Ac0.z*v0.z); af[3]=f2bf(Ac0.w*v0.w);
    af[4]=f2bf(Ac1.x*v1.x); af[5]=f2bf(Ac1.y*v1.y); af[6]=f2bf(Ac1.z*v1.z); af[7]=f2bf(Ac1.w*v1.w);
    const short* sb = sStage[c & 1];
    #pragma unroll
    for (int n = 0; n < 16; ++n) {
      const int row = 16 * n + li;
      short8v bb = *(const short8v*)(sb + row * 32 + 8 * (g ^ ((row >> 1) & 3)));
      acc[n] = __builtin_amdgcn_mfma_f32_16x16x32_bf16(af, bb, acc[n], 0, 0, 0);
    }
    __syncthreads();
    Ac0 = An0; Ac1 = An1;
  }

  // ---- softmax (rows 16wv+4g+r, cols 16n+li); chunk-8 stage is in flight ----
  s1part += __shfl_xor(s1part, 16);
  s1part += __shfl_xor(s1part, 32);
  float s1r[4];
  #pragma unroll
  for (int r = 0; r < 4; ++r) s1r[r] = __shfl(s1part, 4 * g + r);

  float q2v[16];
  #pragma unroll
  for (int n = 0; n < 16; ++n) q2v[n] = q2_ws[b * NTQ + 16 * n + li];

  #pragma unroll
  for (int n = 0; n < 16; ++n)
    #pragma unroll
    for (int r = 0; r < 4; ++r) acc[n][r] += s1r[r] + q2v[n];

  float mx[4], inv[4];
  #pragma unroll
  for (int r = 0; r < 4; ++r) {
    float m0 = acc[0][r];
    #pragma unroll
    for (int n = 1; n < 16; ++n) m0 = fmaxf(m0, acc[n][r]);
    m0 = fmaxf(m0, __shfl_xor(m0, 1));
    m0 = fmaxf(m0, __shfl_xor(m0, 2));
    m0 = fmaxf(m0, __shfl_xor(m0, 4));
    m0 = fmaxf(m0, __shfl_xor(m0, 8));
    mx[r] = m0;
  }
  if (li == 0) {
    #pragma unroll
    for (int r = 0; r < 4; ++r) m_ws[b * NTC + t0 + 16 * wv + 4 * g + r] = mx[r];
  }
  #pragma unroll
  for (int r = 0; r < 4; ++r) {
    float z = 0.f;
    #pragma unroll
    for (int n = 0; n < 16; ++n) { float e = __expf(acc[n][r] - mx[r]); acc[n][r] = e; z += e; }
    z += __shfl_xor(z, 1);
    z += __shfl_xor(z, 2);
    z += __shfl_xor(z, 4);
    z += __shfl_xor(z, 8);
    inv[r] = 1.0f / z;
  }
  #pragma unroll
  for (int n = 0; n < 16; ++n) {
    #pragma unroll
    for (int r = 0; r < 4; ++r)
      sPw[(4 * g + r) * PSTR + 16 * n + li] = f2bf(acc[n][r] * inv[r]);
  }

  // ---- Phase 2: chunks 8..15 (q-chunks of 32) ----
  float4v acc2[16];
  #pragma unroll
  for (int n = 0; n < 16; ++n) acc2[n] = (float4v)0.f;

  for (int cc = 0; cc < 8; ++cc) {
    if (cc < 7) STAGE((cc + 1) & 1, Qtb, 32 * (cc + 1));
    const short* sb = sStage[cc & 1];
    short8v a2 = *(const short8v*)(sPw + li * PSTR + 32 * cc + 8 * g);
    #pragma unroll
    for (int n = 0; n < 16; ++n) {
      const int row = 16 * n + li;
      short8v bb = *(const short8v*)(sb + row * 32 + 8 * (g ^ ((row >> 1) & 3)));
      acc2[n] = __builtin_amdgcn_mfma_f32_16x16x32_bf16(a2, bb, acc2[n], 0, 0, 0);
    }
    if (cc < 7) __syncthreads();
  }

  // ---- epilogue: per-wave LDS transpose, sector-aligned stores ----
  asm volatile("s_waitcnt lgkmcnt(0)" ::: "memory");   // sP reads drained before overlay
  __builtin_amdgcn_sched_barrier(0);
  #pragma unroll
  for (int h = 0; h < 2; ++h) {
    #pragma unroll
    for (int nn = 0; nn < 8; ++nn) {
      const int n = 8 * h + nn;
      #pragma unroll
      for (int r = 0; r < 4; ++r)
        sUw[(4 * g + r) * USTR + 16 * nn + li] = acc2[n][r];
    }
    asm volatile("s_waitcnt lgkmcnt(0)" ::: "memory");
    __builtin_amdgcn_sched_barrier(0);
    #pragma unroll
    for (int r0 = 0; r0 < 16; r0 += 4) {
      const int row = r0 + g;
      #pragma unroll
      for (int j = 0; j < 2; ++j) {
        float4 u = *(const float4*)(sUw + row * USTR + 64 * j + 4 * li);
        const int gcol = 128 * h + 64 * j + 4 * li;
        const float* cp = ctxB + (size_t)(16 * wv + row) * ND + gcol;
        float4 c = *(const float4*)cp;
        const size_t gb = ((size_t)b * NTC + t0 + 16 * wv + row) * 1024 + gcol;
        *(float4*)(G + gb)       = c;
        *(float4*)(G + gb + 256) = u;
        *(float4*)(G + gb + 512) = make_float4(c.x*u.x, c.y*u.y, c.z*u.z, c.w*u.w);
      }
    }
    asm volatile("s_waitcnt lgkmcnt(0)" ::: "memory");
    __builtin_amdgcn_sched_barrier(0);
  }
}

// K2: per (b, t-slice of 128): batch softmax over t of m, partial h
__global__ __launch_bounds__(256) void k2_bt(const float* __restrict__ ctx,
                                             const float* __restrict__ m_ws,
                                             float* __restrict__ h_part) {
  __shared__ __align__(16) float sM[NTC];
  __shared__ float red[32];
  int b = blockIdx.x >> 4;
  int slice = blockIdx.x & 15;
  int tid = threadIdx.x;

  float lm = -1e30f;
  #pragma unroll
  for (int k = 0; k < 8; ++k) {
    float v = m_ws[b * NTC + tid * 8 + k];
    sM[tid * 8 + k] = v;
    lm = fmaxf(lm, v);
  }
  #pragma unroll
  for (int s = 1; s < 64; s <<= 1) lm = fmaxf(lm, __shfl_xor(lm, s));
  if ((tid & 63) == 0) red[tid >> 6] = lm;
  __syncthreads();
  float M = fmaxf(fmaxf(red[0], red[1]), fmaxf(red[2], red[3]));
  float ls = 0.f;
  #pragma unroll
  for (int k = 0; k < 8; ++k) ls += __expf(sM[tid * 8 + k] - M);
  #pragma unroll
  for (int s = 1; s < 64; s <<= 1) ls += __shfl_xor(ls, s);
  if ((tid & 63) == 0) red[16 + (tid >> 6)] = ls;
  __syncthreads();
  float invZ = 1.0f / (red[16] + red[17] + red[18] + red[19]);

  int tbase = slice * 128;
  const float* cb = ctx + ((size_t)b * NTC + tbase) * ND + tid;
  float acc = 0.f;
  #pragma unroll 8
  for (int t = 0; t < 128; ++t) {
    float btv = __expf(sM[tbase + t] - M) * invZ;
    acc += btv * cb[(size_t)t * ND];
  }
  h_part[((size_t)b * 16 + slice) * ND + tid] = acc;
}

__global__ __launch_bounds__(256) void k2b_hred(const float* __restrict__ h_part,
                                                float* __restrict__ h_ws) {
  int b = blockIdx.x;
  int d = threadIdx.x;
  float acc = 0.f;
  #pragma unroll
  for (int s = 0; s < 16; ++s) acc += h_part[((size_t)b * 16 + s) * ND + d];
  h_ws[b * ND + d] = acc;
}

// K3: G[...,768:1024] = C * h[b,:]
__global__ __launch_bounds__(256) void k3_epi(const float* __restrict__ ctx,
                                              const float* __restrict__ h_ws,
                                              float* __restrict__ G) {
  size_t f = (size_t)blockIdx.x * 256 + threadIdx.x;
  size_t e = f * 4;
  int d = (int)(e & 255);
  size_t bt = e >> 8;
  int b = (int)(bt >> 11);
  float4 c = *(const float4*)(ctx + e);
  float4 h = *(const float4*)(h_ws + b * ND + d);
  *(float4*)(G + bt * 1024 + 768 + d) =
      make_float4(c.x * h.x, c.y * h.y, c.z * h.z, c.w * h.w);
}

extern "C" void kernel_launch(void* const* d_in, const int* in_sizes, int n_in,
                              void* d_out, int out_size, void* d_ws, size_t ws_size,
                              hipStream_t stream) {
  const float* ctx = (const float*)d_in[0];
  const float* qry = (const float*)d_in[1];
  const float* w   = (const float*)d_in[2];
  float* G  = (float*)d_out;
  float* ws = (float*)d_ws;
  float* m_ws   = ws + M_OFF;
  float* h_part = ws + HP_OFF;
  float* h_ws   = ws + H_OFF;
  float* q2_ws  = ws + Q2_OFF;
  short* Qbf = (short*)(ws + QBF_OFF);
  short* Qt  = (short*)(ws + QT_OFF);

  k0_prep<<<NB * 8, 256, 0, stream>>>(qry, w, q2_ws, Qbf, Qt);
  k1_main<<<NB * (NTC / 64), 256, 0, stream>>>(ctx, w, Qbf, Qt, q2_ws, m_ws, G);
  k2_bt<<<NB * 16, 256, 0, stream>>>(ctx, m_ws, h_part);
  k2b_hred<<<NB, 256, 0, stream>>>(h_part, h_ws);
  k3_epi<<<16384, 256, 0, stream>>>(ctx, h_ws, G);
}

// Round 6
// 115.888 us; speedup vs baseline: 2.1101x; 1.0396x over previous
//
#include <hip/hip_runtime.h>

#define NB  32
#define NTC 2048
#define NTQ 256
#define ND  256

// ws layout (floats):
// hp2[32][32][260] @0 (p[256], Mloc, zloc, pad2) ; h[32][256] @266240 ;
// q2[32][256] @274432 ; Qbf(bf16) @282624f ; Qt(bf16) @+1M floats
#define HP2_OFF 0
#define H_OFF   266240
#define Q2_OFF  274432
#define QBF_OFF 282624
#define QT_OFF  (282624 + 1048576)

#define PSTR 264   // sP row stride (shorts): 528B, 16B-aligned
#define USTR 130   // sU row stride (floats)

typedef __attribute__((ext_vector_type(8))) short short8v;
typedef __attribute__((ext_vector_type(4))) float float4v;
typedef unsigned int u32;

static __device__ inline short f2bf(float f) {
  union { float f; unsigned u; } v; v.f = f;
  unsigned r = v.u + 0x7FFFu + ((v.u >> 16) & 1u);
  return (short)(r >> 16);
}

static __device__ inline void gload_lds16(const short* g, short* l) {
  __builtin_amdgcn_global_load_lds(
      (const __attribute__((address_space(1))) u32*)g,
      (__attribute__((address_space(3))) u32*)l, 16, 0, 0);
}

// K0: per (b, 32-row q-chunk): Qbf = bf16(Q) row-major; Qt = bf16(Q)^T; q2 = Q.w2
__global__ __launch_bounds__(256) void k0_prep(const float* __restrict__ qry,
                                               const float* __restrict__ w,
                                               float* __restrict__ q2_ws,
                                               short* __restrict__ Qbf,
                                               short* __restrict__ Qt) {
  __shared__ float sRed[8][32];
  const int tid = threadIdx.x;
  const int b = blockIdx.x >> 3;
  const int q0 = (blockIdx.x & 7) << 5;
  const int q = tid & 31;
  const int dc = tid >> 5;
  const float* src = qry + (((size_t)b * NTQ) + q0 + q) * ND + dc * 32;
  const float* w2p = w + ND + dc * 32;

  float vals[32];
  float part = 0.f;
  #pragma unroll
  for (int i = 0; i < 8; ++i) {
    float4 v = *(const float4*)(src + 4 * i);
    float4 u = *(const float4*)(w2p + 4 * i);
    part += v.x*u.x + v.y*u.y + v.z*u.z + v.w*u.w;
    vals[4*i] = v.x; vals[4*i+1] = v.y; vals[4*i+2] = v.z; vals[4*i+3] = v.w;
  }
  short pk[32];
  #pragma unroll
  for (int i = 0; i < 32; ++i) pk[i] = f2bf(vals[i]);

  short* dst = Qbf + ((size_t)b * NTQ + q0 + q) * ND + dc * 32;
  #pragma unroll
  for (int i = 0; i < 4; ++i) *(short8v*)(dst + 8 * i) = *(short8v*)(pk + 8 * i);
  short* dstT = Qt + (size_t)b * NTQ * ND + q0 + q;
  #pragma unroll
  for (int i = 0; i < 32; ++i) dstT[(size_t)(dc * 32 + i) * NTQ] = pk[i];

  part += __shfl_xor(part, 32);
  if ((tid & 32) == 0) sRed[dc][q] = part;
  __syncthreads();
  if (tid < 32) {
    float s = sRed[0][tid] + sRed[2][tid] + sRed[4][tid] + sRed[6][tid];
    q2_ws[b * NTQ + q0 + tid] = s;
  }
}

// K1: per (b, 64-row tile). Double-buffered LDS staging of Q chunks.
// Phase1: S = s1+q2+(C*w3)Q^T. Softmax in-reg -> sP. Phase2: U = P Q.
// Epilogue: G0=C, G1=U, G2=C*U + tile-partial h (p, Mloc, zloc) -> hp2.
__global__ __launch_bounds__(256, 2) void k1_main(const float* __restrict__ ctx,
                                                  const float* __restrict__ w,
                                                  const short* __restrict__ Qbf,
                                                  const short* __restrict__ Qt,
                                                  const float* __restrict__ q2_ws,
                                                  float* __restrict__ hp2,
                                                  float* __restrict__ G) {
  __shared__ __align__(16) short sStage[2][256 * 32];    // 2 x 16KB
  __shared__ __align__(16) short sP_all[4 * 16 * PSTR];  // 33KB per-wave P / sU overlay

  const int tid  = threadIdx.x;
  const int wv   = tid >> 6;
  const int lane = tid & 63;
  const int g    = lane >> 4;
  const int li   = lane & 15;
  const int bid  = blockIdx.x;
  const int obid = (bid & 7) * 128 + (bid >> 3);   // XCD-bijective swizzle
  const int b    = obid >> 5;
  const int tile = obid & 31;
  const int t0   = tile << 6;

  short* sPw = sP_all + wv * (16 * PSTR);
  float* sUw = (float*)sPw;
  // post-phase2 overlays in sStage[0] (free after cc=6 barrier):
  float* sH    = (float*)sStage;          // [4][256]
  float* sMm   = (float*)sStage + 1024;   // [64]
  float* sRedM = (float*)sStage + 1088;   // [4]
  float* sRedZ = (float*)sStage + 1092;   // [4]

  const float* __restrict__ ctxB = ctx + ((size_t)b * NTC + t0) * ND;
  const short* __restrict__ Qb   = Qbf + (size_t)b * NTQ * ND;
  const short* __restrict__ Qtb  = Qt  + (size_t)b * NTQ * ND;

  const int srow = 64 * wv + (lane >> 2);
  const int sblk = lane & 3;

  #define STAGE(buf, src, c0)                                                   \
    { _Pragma("unroll")                                                         \
      for (int j = 0; j < 4; ++j) {                                             \
        const int row_ = srow + 16 * j;                                         \
        const int gi_  = sblk ^ ((row_ >> 1) & 3);                              \
        gload_lds16((src) + (size_t)row_ * 256 + (c0) + 8 * gi_,                \
                    &sStage[buf][wv * 2048 + j * 512]);                         \
      } }

  float4v acc[16];
  #pragma unroll
  for (int n = 0; n < 16; ++n) acc[n] = (float4v)0.f;
  float s1part = 0.f;

  STAGE(0, Qb, 0);
  const float* arow = ctxB + (size_t)(16 * wv + li) * ND + 8 * g;
  float4 Ac0 = *(const float4*)(arow);
  float4 Ac1 = *(const float4*)(arow + 4);
  __syncthreads();

  // ---- Phase 1: chunks 0..7 ----
  for (int c = 0; c < 8; ++c) {
    float4 An0, An1;
    if (c < 7) {
      STAGE((c + 1) & 1, Qb, 32 * (c + 1));
      An0 = *(const float4*)(arow + 32 * (c + 1));
      An1 = *(const float4*)(arow + 32 * (c + 1) + 4);
    } else {
      STAGE(0, Qtb, 0);
    }
    const float* w1p = w + 32 * c + 8 * g;
    const float* w3p = w + 2 * ND + 32 * c + 8 * g;
    float4 u0 = *(const float4*)w1p, u1 = *(const float4*)(w1p + 4);
    float4 v0 = *(const float4*)w3p, v1 = *(const float4*)(w3p + 4);
    s1part += Ac0.x*u0.x + Ac0.y*u0.y + Ac0.z*u0.z + Ac0.w*u0.w
            + Ac1.x*u1.x + Ac1.y*u1.y + Ac1.z*u1.z + Ac1.w*u1.w;
    short8v af;
    af[0]=f2bf(Ac0.x*v0.x); af[1]=f2bf(Ac0.y*v0.y); af[2]=f2bf(Ac0.z*v0.z); af[3]=f2bf(Ac0.w*v0.w);
    af[4]=f2bf(Ac1.x*v1.x); af[5]=f2bf(Ac1.y*v1.y); af[6]=f2bf(Ac1.z*v1.z); af[7]=f2bf(Ac1.w*v1.w);
    const short* sb = sStage[c & 1];
    #pragma unroll
    for (int n = 0; n < 16; ++n) {
      const int row = 16 * n + li;
      short8v bb = *(const short8v*)(sb + row * 32 + 8 * (g ^ ((row >> 1) & 3)));
      acc[n] = __builtin_amdgcn_mfma_f32_16x16x32_bf16(af, bb, acc[n], 0, 0, 0);
    }
    __syncthreads();
    Ac0 = An0; Ac1 = An1;
  }

  // ---- softmax (rows 16wv+4g+r, cols 16n+li) ----
  s1part += __shfl_xor(s1part, 16);
  s1part += __shfl_xor(s1part, 32);
  float s1r[4];
  #pragma unroll
  for (int r = 0; r < 4; ++r) s1r[r] = __shfl(s1part, 4 * g + r);

  float q2v[16];
  #pragma unroll
  for (int n = 0; n < 16; ++n) q2v[n] = q2_ws[b * NTQ + 16 * n + li];

  #pragma unroll
  for (int n = 0; n < 16; ++n)
    #pragma unroll
    for (int r = 0; r < 4; ++r) acc[n][r] += s1r[r] + q2v[n];

  float mx[4], inv[4];
  #pragma unroll
  for (int r = 0; r < 4; ++r) {
    float m0 = acc[0][r];
    #pragma unroll
    for (int n = 1; n < 16; ++n) m0 = fmaxf(m0, acc[n][r]);
    m0 = fmaxf(m0, __shfl_xor(m0, 1));
    m0 = fmaxf(m0, __shfl_xor(m0, 2));
    m0 = fmaxf(m0, __shfl_xor(m0, 4));
    m0 = fmaxf(m0, __shfl_xor(m0, 8));
    mx[r] = m0;
  }
  #pragma unroll
  for (int r = 0; r < 4; ++r) {
    float z = 0.f;
    #pragma unroll
    for (int n = 0; n < 16; ++n) { float e = __expf(acc[n][r] - mx[r]); acc[n][r] = e; z += e; }
    z += __shfl_xor(z, 1);
    z += __shfl_xor(z, 2);
    z += __shfl_xor(z, 4);
    z += __shfl_xor(z, 8);
    inv[r] = 1.0f / z;
  }
  #pragma unroll
  for (int n = 0; n < 16; ++n) {
    #pragma unroll
    for (int r = 0; r < 4; ++r)
      sPw[(4 * g + r) * PSTR + 16 * n + li] = f2bf(acc[n][r] * inv[r]);
  }

  // ---- Phase 2: U = P Q, chunks 0..7 of q ----
  float4v acc2[16];
  #pragma unroll
  for (int n = 0; n < 16; ++n) acc2[n] = (float4v)0.f;

  for (int cc = 0; cc < 8; ++cc) {
    if (cc < 7) STAGE((cc + 1) & 1, Qtb, 32 * (cc + 1));
    const short* sb = sStage[cc & 1];
    short8v a2 = *(const short8v*)(sPw + li * PSTR + 32 * cc + 8 * g);
    #pragma unroll
    for (int n = 0; n < 16; ++n) {
      const int row = 16 * n + li;
      short8v bb = *(const short8v*)(sb + row * 32 + 8 * (g ^ ((row >> 1) & 3)));
      acc2[n] = __builtin_amdgcn_mfma_f32_16x16x32_bf16(a2, bb, acc2[n], 0, 0, 0);
    }
    if (cc < 7) __syncthreads();
  }

  // ---- tile-level b_t partials: Mloc, zloc, per-row weights ----
  if (li == 0) {
    #pragma unroll
    for (int r = 0; r < 4; ++r) sMm[16 * wv + 4 * g + r] = mx[r];
  }
  float lm = fmaxf(fmaxf(mx[0], mx[1]), fmaxf(mx[2], mx[3]));
  lm = fmaxf(lm, __shfl_xor(lm, 16));
  lm = fmaxf(lm, __shfl_xor(lm, 32));
  if (lane == 0) sRedM[wv] = lm;
  __syncthreads();
  const float Mloc = fmaxf(fmaxf(sRedM[0], sRedM[1]), fmaxf(sRedM[2], sRedM[3]));
  float zp = 0.f;
  #pragma unroll
  for (int r = 0; r < 4; ++r) zp += __expf(mx[r] - Mloc);
  zp += __shfl_xor(zp, 16);
  zp += __shfl_xor(zp, 32);
  if (lane == 0) sRedZ[wv] = zp;
  float wgt[4];
  #pragma unroll
  for (int k = 0; k < 4; ++k) wgt[k] = __expf(sMm[16 * wv + 4 * k + g] - Mloc);

  // ---- epilogue: LDS transpose, sector stores, partial-h accumulation ----
  float4 ha[2][2];
  #pragma unroll
  for (int h = 0; h < 2; ++h)
    #pragma unroll
    for (int j = 0; j < 2; ++j) ha[h][j] = make_float4(0.f, 0.f, 0.f, 0.f);

  asm volatile("s_waitcnt lgkmcnt(0)" ::: "memory");
  __builtin_amdgcn_sched_barrier(0);
  #pragma unroll
  for (int h = 0; h < 2; ++h) {
    #pragma unroll
    for (int nn = 0; nn < 8; ++nn) {
      const int n = 8 * h + nn;
      #pragma unroll
      for (int r = 0; r < 4; ++r)
        sUw[(4 * g + r) * USTR + 16 * nn + li] = acc2[n][r];
    }
    asm volatile("s_waitcnt lgkmcnt(0)" ::: "memory");
    __builtin_amdgcn_sched_barrier(0);
    #pragma unroll
    for (int r0 = 0; r0 < 16; r0 += 4) {
      const int row = r0 + g;
      const float wk = wgt[r0 >> 2];
      #pragma unroll
      for (int j = 0; j < 2; ++j) {
        float4 u = *(const float4*)(sUw + row * USTR + 64 * j + 4 * li);
        const int gcol = 128 * h + 64 * j + 4 * li;
        const float* cp = ctxB + (size_t)(16 * wv + row) * ND + gcol;
        float4 c = *(const float4*)cp;
        const size_t gb = ((size_t)b * NTC + t0 + 16 * wv + row) * 1024 + gcol;
        *(float4*)(G + gb)       = c;
        *(float4*)(G + gb + 256) = u;
        *(float4*)(G + gb + 512) = make_float4(c.x*u.x, c.y*u.y, c.z*u.z, c.w*u.w);
        ha[h][j].x += wk * c.x; ha[h][j].y += wk * c.y;
        ha[h][j].z += wk * c.z; ha[h][j].w += wk * c.w;
      }
    }
    asm volatile("s_waitcnt lgkmcnt(0)" ::: "memory");
    __builtin_amdgcn_sched_barrier(0);
  }

  // reduce ha across g (rows), then across waves via sH
  #pragma unroll
  for (int h = 0; h < 2; ++h)
    #pragma unroll
    for (int j = 0; j < 2; ++j) {
      float* f = (float*)&ha[h][j];
      #pragma unroll
      for (int e = 0; e < 4; ++e) {
        f[e] += __shfl_xor(f[e], 16);
        f[e] += __shfl_xor(f[e], 32);
      }
    }
  if (g == 0) {
    #pragma unroll
    for (int h = 0; h < 2; ++h)
      #pragma unroll
      for (int j = 0; j < 2; ++j)
        *(float4*)(sH + wv * 256 + 128 * h + 64 * j + 4 * li) = ha[h][j];
  }
  __syncthreads();
  float* hp = hp2 + (size_t)(b * 32 + tile) * 260;
  {
    float ph = sH[tid & 255] + sH[256 + (tid & 255)] + sH[512 + (tid & 255)] + sH[768 + (tid & 255)];
    if (tid < 256) hp[tid] = ph;
  }
  if (tid == 0) {
    hp[256] = Mloc;
    hp[257] = sRedZ[0] + sRedZ[1] + sRedZ[2] + sRedZ[3];
  }
}

// K2h: per batch, combine 32 tile partials -> h[b][256]
__global__ __launch_bounds__(256) void k2h(const float* __restrict__ hp2,
                                           float* __restrict__ h_ws) {
  __shared__ float sM2[32], sZ2[32];
  const int b = blockIdx.x;
  const int tid = threadIdx.x;
  if (tid < 32) {
    sM2[tid] = hp2[(size_t)(b * 32 + tid) * 260 + 256];
    sZ2[tid] = hp2[(size_t)(b * 32 + tid) * 260 + 257];
  }
  __syncthreads();
  float M = -1e30f;
  #pragma unroll
  for (int i = 0; i < 32; ++i) M = fmaxf(M, sM2[i]);
  float Z = 0.f;
  float a = 0.f;
  #pragma unroll
  for (int i = 0; i < 32; ++i) {
    float e = __expf(sM2[i] - M);
    Z += sZ2[i] * e;
    a += hp2[(size_t)(b * 32 + i) * 260 + tid] * e;
  }
  h_ws[b * 256 + tid] = a / Z;
}

// K3: G[...,768:1024] = C * h[b,:]
__global__ __launch_bounds__(256) void k3_epi(const float* __restrict__ ctx,
                                              const float* __restrict__ h_ws,
                                              float* __restrict__ G) {
  size_t f = (size_t)blockIdx.x * 256 + threadIdx.x;
  size_t e = f * 4;
  int d = (int)(e & 255);
  size_t bt = e >> 8;
  int b = (int)(bt >> 11);
  float4 c = *(const float4*)(ctx + e);
  float4 h = *(const float4*)(h_ws + b * ND + d);
  *(float4*)(G + bt * 1024 + 768 + d) =
      make_float4(c.x * h.x, c.y * h.y, c.z * h.z, c.w * h.w);
}

extern "C" void kernel_launch(void* const* d_in, const int* in_sizes, int n_in,
                              void* d_out, int out_size, void* d_ws, size_t ws_size,
                              hipStream_t stream) {
  const float* ctx = (const float*)d_in[0];
  const float* qry = (const float*)d_in[1];
  const float* w   = (const float*)d_in[2];
  float* G  = (float*)d_out;
  float* ws = (float*)d_ws;
  float* hp2   = ws + HP2_OFF;
  float* h_ws  = ws + H_OFF;
  float* q2_ws = ws + Q2_OFF;
  short* Qbf = (short*)(ws + QBF_OFF);
  short* Qt  = (short*)(ws + QT_OFF);

  k0_prep<<<NB * 8, 256, 0, stream>>>(qry, w, q2_ws, Qbf, Qt);
  k1_main<<<NB * (NTC / 64), 256, 0, stream>>>(ctx, w, Qbf, Qt, q2_ws, hp2, G);
  k2h<<<NB, 256, 0, stream>>>(hp2, h_ws);
  k3_epi<<<16384, 256, 0, stream>>>(ctx, h_ws, G);
}

// Round 7
// 108.246 us; speedup vs baseline: 2.2591x; 1.0706x over previous
//
#include <hip/hip_runtime.h>

#define NB  32
#define NTC 2048
#define NTQ 256
#define ND  256

// ws layout (floats):
// hp2[32][32][260] @0 ; h[32][256] @266240 ; q2[32][256] @274432 ;
// Qbf(bf16) @282624f ; Qt(bf16) @+1M floats
#define HP2_OFF 0
#define H_OFF   266240
#define Q2_OFF  274432
#define QBF_OFF 282624
#define QT_OFF  (282624 + 1048576)

#define PSTR 264   // sP row stride (shorts)
#define USTR 130   // sU row stride (floats)

typedef __attribute__((ext_vector_type(8))) short short8v;
typedef __attribute__((ext_vector_type(4))) float float4v;
typedef unsigned int u32;

static __device__ inline short f2bf(float f) {
  union { float f; unsigned u; } v; v.f = f;
  unsigned r = v.u + 0x7FFFu + ((v.u >> 16) & 1u);
  return (short)(r >> 16);
}

static __device__ inline void gload_lds16(const short* g, short* l) {
  __builtin_amdgcn_global_load_lds(
      (const __attribute__((address_space(1))) u32*)g,
      (__attribute__((address_space(3))) u32*)l, 16, 0, 0);
}

// K0: per (b, 32-row q-chunk): Qbf = bf16(Q); Qt = bf16(Q)^T; q2 = Q.w2
__global__ __launch_bounds__(256) void k0_prep(const float* __restrict__ qry,
                                               const float* __restrict__ w,
                                               float* __restrict__ q2_ws,
                                               short* __restrict__ Qbf,
                                               short* __restrict__ Qt) {
  __shared__ float sRed[8][32];
  const int tid = threadIdx.x;
  const int b = blockIdx.x >> 3;
  const int q0 = (blockIdx.x & 7) << 5;
  const int q = tid & 31;
  const int dc = tid >> 5;
  const float* src = qry + (((size_t)b * NTQ) + q0 + q) * ND + dc * 32;
  const float* w2p = w + ND + dc * 32;

  float vals[32];
  float part = 0.f;
  #pragma unroll
  for (int i = 0; i < 8; ++i) {
    float4 v = *(const float4*)(src + 4 * i);
    float4 u = *(const float4*)(w2p + 4 * i);
    part += v.x*u.x + v.y*u.y + v.z*u.z + v.w*u.w;
    vals[4*i] = v.x; vals[4*i+1] = v.y; vals[4*i+2] = v.z; vals[4*i+3] = v.w;
  }
  short pk[32];
  #pragma unroll
  for (int i = 0; i < 32; ++i) pk[i] = f2bf(vals[i]);

  short* dst = Qbf + ((size_t)b * NTQ + q0 + q) * ND + dc * 32;
  #pragma unroll
  for (int i = 0; i < 4; ++i) *(short8v*)(dst + 8 * i) = *(short8v*)(pk + 8 * i);
  short* dstT = Qt + (size_t)b * NTQ * ND + q0 + q;
  #pragma unroll
  for (int i = 0; i < 32; ++i) dstT[(size_t)(dc * 32 + i) * NTQ] = pk[i];

  part += __shfl_xor(part, 32);
  if ((tid & 32) == 0) sRed[dc][q] = part;
  __syncthreads();
  if (tid < 32) {
    float s = sRed[0][tid] + sRed[2][tid] + sRed[4][tid] + sRed[6][tid];
    q2_ws[b * NTQ + q0 + tid] = s;
  }
}

// K1: per (b, 64-row tile). Counted-vmcnt double-barrier staging pipeline.
// Phase1: S = s1+q2+(C*w3)Q^T, G0=C written inline. Softmax in-reg -> sP.
// Phase2: U = P Q. Epilogue: G1=U, G2=C*U + tile-partial h -> hp2.
__global__ __launch_bounds__(256, 2) void k1_main(const float* __restrict__ ctx,
                                                  const float* __restrict__ w,
                                                  const short* __restrict__ Qbf,
                                                  const short* __restrict__ Qt,
                                                  const float* __restrict__ q2_ws,
                                                  float* __restrict__ hp2,
                                                  float* __restrict__ G) {
  __shared__ __align__(16) short sStage[2][256 * 32];    // 2 x 16KB
  __shared__ __align__(16) short sP_all[4 * 16 * PSTR];  // 33KB per-wave P / sU overlay
  __shared__ __align__(16) float sW[768];                // w1|w2|w3

  const int tid  = threadIdx.x;
  const int wv   = tid >> 6;
  const int lane = tid & 63;
  const int g    = lane >> 4;
  const int li   = lane & 15;
  const int bid  = blockIdx.x;
  const int obid = (bid & 7) * 128 + (bid >> 3);   // XCD-bijective swizzle
  const int b    = obid >> 5;
  const int tile = obid & 31;
  const int t0   = tile << 6;

  short* sPw = sP_all + wv * (16 * PSTR);
  float* sUw = (float*)sPw;
  float* sH    = (float*)sStage;          // [4][256] overlay (post-phase2)
  float* sMm   = (float*)sStage + 1024;   // [64]
  float* sRedM = (float*)sStage + 1088;   // [4]
  float* sRedZ = (float*)sStage + 1092;   // [4]

  const float* __restrict__ ctxB = ctx + ((size_t)b * NTC + t0) * ND;
  const short* __restrict__ Qb   = Qbf + (size_t)b * NTQ * ND;
  const short* __restrict__ Qtb  = Qt  + (size_t)b * NTQ * ND;

  const int srow = 64 * wv + (lane >> 2);
  const int sblk = lane & 3;

  #define STAGE(buf, src, c0)                                                   \
    { _Pragma("unroll")                                                         \
      for (int j = 0; j < 4; ++j) {                                             \
        const int row_ = srow + 16 * j;                                         \
        const int gi_  = sblk ^ ((row_ >> 1) & 3);                              \
        gload_lds16((src) + (size_t)row_ * 256 + (c0) + 8 * gi_,                \
                    &sStage[buf][wv * 2048 + j * 512]);                         \
      } }

  float4v acc[16];
  #pragma unroll
  for (int n = 0; n < 16; ++n) acc[n] = (float4v)0.f;
  float s1part = 0.f;

  // ---- prologue: q2 preload, w->LDS, stage chunk 0, A(0); full drain once ----
  float q2v[16];
  #pragma unroll
  for (int n = 0; n < 16; ++n) q2v[n] = q2_ws[b * NTQ + 16 * n + li];
  if (tid < 192) *(float4*)(sW + 4 * tid) = *(const float4*)(w + 4 * tid);
  STAGE(0, Qb, 0);
  const float* arow = ctxB + (size_t)(16 * wv + li) * ND + 8 * g;
  float4 Ac0 = *(const float4*)(arow);
  float4 Ac1 = *(const float4*)(arow + 4);
  asm volatile("s_waitcnt vmcnt(0) lgkmcnt(0)" ::: "memory");
  __builtin_amdgcn_s_barrier();
  __builtin_amdgcn_sched_barrier(0);

  const size_t gb0 = ((size_t)b * NTC + t0 + 16 * wv + li) * 1024 + 8 * g;

  // ---- Phase 1: chunks 0..7, counted-vmcnt two-barrier pipeline ----
  #pragma unroll
  for (int c = 0; c < 8; ++c) {
    // pack af from Ac(c) and w (LDS); s1 partial
    float4 u0 = *(const float4*)(sW + 32 * c + 8 * g);
    float4 u1 = *(const float4*)(sW + 32 * c + 8 * g + 4);
    float4 v0 = *(const float4*)(sW + 512 + 32 * c + 8 * g);
    float4 v1 = *(const float4*)(sW + 512 + 32 * c + 8 * g + 4);
    s1part += Ac0.x*u0.x + Ac0.y*u0.y + Ac0.z*u0.z + Ac0.w*u0.w
            + Ac1.x*u1.x + Ac1.y*u1.y + Ac1.z*u1.z + Ac1.w*u1.w;
    short8v af;
    af[0]=f2bf(Ac0.x*v0.x); af[1]=f2bf(Ac0.y*v0.y); af[2]=f2bf(Ac0.z*v0.z); af[3]=f2bf(Ac0.w*v0.w);
    af[4]=f2bf(Ac1.x*v1.x); af[5]=f2bf(Ac1.y*v1.y); af[6]=f2bf(Ac1.z*v1.z); af[7]=f2bf(Ac1.w*v1.w);
    __builtin_amdgcn_sched_barrier(0);
    // prefetch A(c+1) [2 loads], then stage next chunk [4 loads] — order pinned
    float4 An0, An1;
    if (c < 7) {
      An0 = *(const float4*)(arow + 32 * (c + 1));
      An1 = *(const float4*)(arow + 32 * (c + 1) + 4);
    }
    __builtin_amdgcn_sched_barrier(0);
    if (c < 7) { STAGE((c + 1) & 1, Qb, 32 * (c + 1)); }
    else       { STAGE(0, Qtb, 0); }
    __builtin_amdgcn_sched_barrier(0);
    asm volatile("s_waitcnt vmcnt(6)" ::: "memory");   // chunk-c stage complete
    __builtin_amdgcn_s_barrier();
    __builtin_amdgcn_sched_barrier(0);
    // MFMA on chunk c + G0 stores of Ac(c)
    const short* sb = sStage[c & 1];
    #pragma unroll
    for (int n = 0; n < 16; ++n) {
      const int row = 16 * n + li;
      short8v bb = *(const short8v*)(sb + row * 32 + 8 * (g ^ ((row >> 1) & 3)));
      acc[n] = __builtin_amdgcn_mfma_f32_16x16x32_bf16(af, bb, acc[n], 0, 0, 0);
    }
    *(float4*)(G + gb0 + 32 * c)     = Ac0;   // G0 = C (spread writes)
    *(float4*)(G + gb0 + 32 * c + 4) = Ac1;
    __builtin_amdgcn_sched_barrier(0);
    __builtin_amdgcn_s_barrier();             // readers done before next overwrite
    __builtin_amdgcn_sched_barrier(0);
    Ac0 = An0; Ac1 = An1;
  }

  // ---- softmax (rows 16wv+4g+r, cols 16n+li) ----
  s1part += __shfl_xor(s1part, 16);
  s1part += __shfl_xor(s1part, 32);
  float s1r[4];
  #pragma unroll
  for (int r = 0; r < 4; ++r) s1r[r] = __shfl(s1part, 4 * g + r);

  #pragma unroll
  for (int n = 0; n < 16; ++n)
    #pragma unroll
    for (int r = 0; r < 4; ++r) acc[n][r] += s1r[r] + q2v[n];

  float mx[4], inv[4];
  #pragma unroll
  for (int r = 0; r < 4; ++r) {
    float m0 = acc[0][r];
    #pragma unroll
    for (int n = 1; n < 16; ++n) m0 = fmaxf(m0, acc[n][r]);
    m0 = fmaxf(m0, __shfl_xor(m0, 1));
    m0 = fmaxf(m0, __shfl_xor(m0, 2));
    m0 = fmaxf(m0, __shfl_xor(m0, 4));
    m0 = fmaxf(m0, __shfl_xor(m0, 8));
    mx[r] = m0;
  }
  #pragma unroll
  for (int r = 0; r < 4; ++r) {
    float z = 0.f;
    #pragma unroll
    for (int n = 0; n < 16; ++n) { float e = __expf(acc[n][r] - mx[r]); acc[n][r] = e; z += e; }
    z += __shfl_xor(z, 1);
    z += __shfl_xor(z, 2);
    z += __shfl_xor(z, 4);
    z += __shfl_xor(z, 8);
    inv[r] = 1.0f / z;
  }
  #pragma unroll
  for (int n = 0; n < 16; ++n) {
    #pragma unroll
    for (int r = 0; r < 4; ++r)
      sPw[(4 * g + r) * PSTR + 16 * n + li] = f2bf(acc[n][r] * inv[r]);
  }

  // ---- Phase 2: U = P Q, counted-vmcnt pipeline (qt chunk 0 already in flight) ----
  float4v acc2[16];
  #pragma unroll
  for (int n = 0; n < 16; ++n) acc2[n] = (float4v)0.f;

  #pragma unroll
  for (int cc = 0; cc < 8; ++cc) {
    short8v a2 = *(const short8v*)(sPw + li * PSTR + 32 * cc + 8 * g);
    __builtin_amdgcn_sched_barrier(0);
    if (cc < 7) { STAGE((cc + 1) & 1, Qtb, 32 * (cc + 1)); }
    __builtin_amdgcn_sched_barrier(0);
    if (cc < 7) asm volatile("s_waitcnt vmcnt(4)" ::: "memory");
    else        asm volatile("s_waitcnt vmcnt(0)" ::: "memory");
    __builtin_amdgcn_s_barrier();
    __builtin_amdgcn_sched_barrier(0);
    const short* sb = sStage[cc & 1];
    #pragma unroll
    for (int n = 0; n < 16; ++n) {
      const int row = 16 * n + li;
      short8v bb = *(const short8v*)(sb + row * 32 + 8 * (g ^ ((row >> 1) & 3)));
      acc2[n] = __builtin_amdgcn_mfma_f32_16x16x32_bf16(a2, bb, acc2[n], 0, 0, 0);
    }
    __builtin_amdgcn_sched_barrier(0);
    __builtin_amdgcn_s_barrier();
    __builtin_amdgcn_sched_barrier(0);
  }

  // ---- tile-level b_t partials ----
  if (li == 0) {
    #pragma unroll
    for (int r = 0; r < 4; ++r) sMm[16 * wv + 4 * g + r] = mx[r];
  }
  float lm = fmaxf(fmaxf(mx[0], mx[1]), fmaxf(mx[2], mx[3]));
  lm = fmaxf(lm, __shfl_xor(lm, 16));
  lm = fmaxf(lm, __shfl_xor(lm, 32));
  if (lane == 0) sRedM[wv] = lm;
  __syncthreads();
  const float Mloc = fmaxf(fmaxf(sRedM[0], sRedM[1]), fmaxf(sRedM[2], sRedM[3]));
  float zp = 0.f;
  #pragma unroll
  for (int r = 0; r < 4; ++r) zp += __expf(mx[r] - Mloc);
  zp += __shfl_xor(zp, 16);
  zp += __shfl_xor(zp, 32);
  if (lane == 0) sRedZ[wv] = zp;
  float wgt[4];
  #pragma unroll
  for (int k = 0; k < 4; ++k) wgt[k] = __expf(sMm[16 * wv + 4 * k + g] - Mloc);

  // ---- epilogue: LDS transpose, sector stores of G1/G2, partial-h ----
  float4 ha[2][2];
  #pragma unroll
  for (int h = 0; h < 2; ++h)
    #pragma unroll
    for (int j = 0; j < 2; ++j) ha[h][j] = make_float4(0.f, 0.f, 0.f, 0.f);

  asm volatile("s_waitcnt lgkmcnt(0)" ::: "memory");
  __builtin_amdgcn_sched_barrier(0);
  #pragma unroll
  for (int h = 0; h < 2; ++h) {
    #pragma unroll
    for (int nn = 0; nn < 8; ++nn) {
      const int n = 8 * h + nn;
      #pragma unroll
      for (int r = 0; r < 4; ++r)
        sUw[(4 * g + r) * USTR + 16 * nn + li] = acc2[n][r];
    }
    asm volatile("s_waitcnt lgkmcnt(0)" ::: "memory");
    __builtin_amdgcn_sched_barrier(0);
    #pragma unroll
    for (int r0 = 0; r0 < 16; r0 += 4) {
      const int row = r0 + g;
      const float wk = wgt[r0 >> 2];
      #pragma unroll
      for (int j = 0; j < 2; ++j) {
        float4 u = *(const float4*)(sUw + row * USTR + 64 * j + 4 * li);
        const int gcol = 128 * h + 64 * j + 4 * li;
        const float* cp = ctxB + (size_t)(16 * wv + row) * ND + gcol;
        float4 c = *(const float4*)cp;
        const size_t gb = ((size_t)b * NTC + t0 + 16 * wv + row) * 1024 + gcol;
        *(float4*)(G + gb + 256) = u;
        *(float4*)(G + gb + 512) = make_float4(c.x*u.x, c.y*u.y, c.z*u.z, c.w*u.w);
        ha[h][j].x += wk * c.x; ha[h][j].y += wk * c.y;
        ha[h][j].z += wk * c.z; ha[h][j].w += wk * c.w;
      }
    }
    asm volatile("s_waitcnt lgkmcnt(0)" ::: "memory");
    __builtin_amdgcn_sched_barrier(0);
  }

  #pragma unroll
  for (int h = 0; h < 2; ++h)
    #pragma unroll
    for (int j = 0; j < 2; ++j) {
      float* f = (float*)&ha[h][j];
      #pragma unroll
      for (int e = 0; e < 4; ++e) {
        f[e] += __shfl_xor(f[e], 16);
        f[e] += __shfl_xor(f[e], 32);
      }
    }
  if (g == 0) {
    #pragma unroll
    for (int h = 0; h < 2; ++h)
      #pragma unroll
      for (int j = 0; j < 2; ++j)
        *(float4*)(sH + wv * 256 + 128 * h + 64 * j + 4 * li) = ha[h][j];
  }
  __syncthreads();
  float* hp = hp2 + (size_t)(b * 32 + tile) * 260;
  {
    float ph = sH[tid & 255] + sH[256 + (tid & 255)] + sH[512 + (tid & 255)] + sH[768 + (tid & 255)];
    if (tid < 256) hp[tid] = ph;
  }
  if (tid == 0) {
    hp[256] = Mloc;
    hp[257] = sRedZ[0] + sRedZ[1] + sRedZ[2] + sRedZ[3];
  }
  #undef STAGE
}

// K2h: per batch, combine 32 tile partials -> h[b][256]
__global__ __launch_bounds__(256) void k2h(const float* __restrict__ hp2,
                                           float* __restrict__ h_ws) {
  __shared__ float sM2[32], sZ2[32];
  const int b = blockIdx.x;
  const int tid = threadIdx.x;
  if (tid < 32) {
    sM2[tid] = hp2[(size_t)(b * 32 + tid) * 260 + 256];
    sZ2[tid] = hp2[(size_t)(b * 32 + tid) * 260 + 257];
  }
  __syncthreads();
  float M = -1e30f;
  #pragma unroll
  for (int i = 0; i < 32; ++i) M = fmaxf(M, sM2[i]);
  float Z = 0.f;
  float a = 0.f;
  #pragma unroll
  for (int i = 0; i < 32; ++i) {
    float e = __expf(sM2[i] - M);
    Z += sZ2[i] * e;
    a += hp2[(size_t)(b * 32 + i) * 260 + tid] * e;
  }
  h_ws[b * 256 + tid] = a / Z;
}

// K3: G[...,768:1024] = C * h[b,:]
__global__ __launch_bounds__(256) void k3_epi(const float* __restrict__ ctx,
                                              const float* __restrict__ h_ws,
                                              float* __restrict__ G) {
  size_t f = (size_t)blockIdx.x * 256 + threadIdx.x;
  size_t e = f * 4;
  int d = (int)(e & 255);
  size_t bt = e >> 8;
  int b = (int)(bt >> 11);
  float4 c = *(const float4*)(ctx + e);
  float4 h = *(const float4*)(h_ws + b * ND + d);
  *(float4*)(G + bt * 1024 + 768 + d) =
      make_float4(c.x * h.x, c.y * h.y, c.z * h.z, c.w * h.w);
}

extern "C" void kernel_launch(void* const* d_in, const int* in_sizes, int n_in,
                              void* d_out, int out_size, void* d_ws, size_t ws_size,
                              hipStream_t stream) {
  const float* ctx = (const float*)d_in[0];
  const float* qry = (const float*)d_in[1];
  const float* w   = (const float*)d_in[2];
  float* G  = (float*)d_out;
  float* ws = (float*)d_ws;
  float* hp2   = ws + HP2_OFF;
  float* h_ws  = ws + H_OFF;
  float* q2_ws = ws + Q2_OFF;
  short* Qbf = (short*)(ws + QBF_OFF);
  short* Qt  = (short*)(ws + QT_OFF);

  k0_prep<<<NB * 8, 256, 0, stream>>>(qry, w, q2_ws, Qbf, Qt);
  k1_main<<<NB * (NTC / 64), 256, 0, stream>>>(ctx, w, Qbf, Qt, q2_ws, hp2, G);
  k2h<<<NB, 256, 0, stream>>>(hp2, h_ws);
  k3_epi<<<16384, 256, 0, stream>>>(ctx, h_ws, G);
}

// Round 8
// 103.508 us; speedup vs baseline: 2.3625x; 1.0458x over previous
//
#include <hip/hip_runtime.h>

#define NB  32
#define NTC 2048
#define NTQ 256
#define ND  256

// ws layout (floats):
// hp2[32][32][260] @0 ; h[32][256] @266240 ; q2[32][256] @274432 ;
// Qbf(bf16) @282624f ; Qt(bf16) @+1M floats
#define HP2_OFF 0
#define H_OFF   266240
#define Q2_OFF  274432
#define QBF_OFF 282624
#define QT_OFF  (282624 + 1048576)

#define PSTR 264   // sP row stride (shorts)

typedef __attribute__((ext_vector_type(8))) short short8v;
typedef __attribute__((ext_vector_type(4))) float float4v;
typedef unsigned int u32;

static __device__ inline short f2bf(float f) {
  union { float f; unsigned u; } v; v.f = f;
  unsigned r = v.u + 0x7FFFu + ((v.u >> 16) & 1u);
  return (short)(r >> 16);
}

static __device__ inline void gload_lds16(const short* g, short* l) {
  __builtin_amdgcn_global_load_lds(
      (const __attribute__((address_space(1))) u32*)g,
      (__attribute__((address_space(3))) u32*)l, 16, 0, 0);
}

// K0: per (b, 32-row q-chunk): Qbf = bf16(Q); Qt = bf16(Q)^T; q2 = Q.w2
__global__ __launch_bounds__(256) void k0_prep(const float* __restrict__ qry,
                                               const float* __restrict__ w,
                                               float* __restrict__ q2_ws,
                                               short* __restrict__ Qbf,
                                               short* __restrict__ Qt) {
  __shared__ float sRed[8][32];
  const int tid = threadIdx.x;
  const int b = blockIdx.x >> 3;
  const int q0 = (blockIdx.x & 7) << 5;
  const int q = tid & 31;
  const int dc = tid >> 5;
  const float* src = qry + (((size_t)b * NTQ) + q0 + q) * ND + dc * 32;
  const float* w2p = w + ND + dc * 32;

  float vals[32];
  float part = 0.f;
  #pragma unroll
  for (int i = 0; i < 8; ++i) {
    float4 v = *(const float4*)(src + 4 * i);
    float4 u = *(const float4*)(w2p + 4 * i);
    part += v.x*u.x + v.y*u.y + v.z*u.z + v.w*u.w;
    vals[4*i] = v.x; vals[4*i+1] = v.y; vals[4*i+2] = v.z; vals[4*i+3] = v.w;
  }
  short pk[32];
  #pragma unroll
  for (int i = 0; i < 32; ++i) pk[i] = f2bf(vals[i]);

  short* dst = Qbf + ((size_t)b * NTQ + q0 + q) * ND + dc * 32;
  #pragma unroll
  for (int i = 0; i < 4; ++i) *(short8v*)(dst + 8 * i) = *(short8v*)(pk + 8 * i);
  short* dstT = Qt + (size_t)b * NTQ * ND + q0 + q;
  #pragma unroll
  for (int i = 0; i < 32; ++i) dstT[(size_t)(dc * 32 + i) * NTQ] = pk[i];

  part += __shfl_xor(part, 32);
  if ((tid & 32) == 0) sRed[dc][q] = part;
  __syncthreads();
  if (tid < 32) {
    float s = sRed[0][tid] + sRed[2][tid] + sRed[4][tid] + sRed[6][tid];
    q2_ws[b * NTQ + q0 + tid] = s;
  }
}

// K1: per (b, 64-row tile). Counted-vmcnt pipeline, both phases.
// Phase1 (q-major): S = s1+q2+(C*w3)Q^T, G0=C inline. Softmax in-reg -> sP.
// Phase2 (d-major): per 32-d chunk, full-K U = P Q, then G1=U, G2=C*U and
// partial-h inline. No tail epilogue.
__global__ __launch_bounds__(256, 2) void k1_main(const float* __restrict__ ctx,
                                                  const float* __restrict__ w,
                                                  const short* __restrict__ Qbf,
                                                  const short* __restrict__ Qt,
                                                  const float* __restrict__ q2_ws,
                                                  float* __restrict__ hp2,
                                                  float* __restrict__ G) {
  __shared__ __align__(16) short sStage[2][256 * 32];    // 2 x 16KB
  __shared__ __align__(16) short sP_all[4 * 16 * PSTR];  // 33KB per-wave P
  __shared__ __align__(16) float sW[768];                // w1|w2|w3
  __shared__ __align__(16) float sHall[4][256];          // per-wave partial h
  __shared__ float sRedM[4], sRedZ[4];

  const int tid  = threadIdx.x;
  const int wv   = tid >> 6;
  const int lane = tid & 63;
  const int g    = lane >> 4;
  const int li   = lane & 15;
  const int bid  = blockIdx.x;
  const int obid = (bid & 7) * 128 + (bid >> 3);   // XCD-bijective swizzle
  const int b    = obid >> 5;
  const int tile = obid & 31;
  const int t0   = tile << 6;

  short* sPw = sP_all + wv * (16 * PSTR);

  const float* __restrict__ ctxB = ctx + ((size_t)b * NTC + t0) * ND;
  const short* __restrict__ Qb   = Qbf + (size_t)b * NTQ * ND;
  const short* __restrict__ Qtb  = Qt  + (size_t)b * NTQ * ND;

  const int srow = 64 * wv + (lane >> 2);
  const int sblk = lane & 3;

  // Phase-1 staging: [256 q][32 k] chunk, granule (8-short) swizzle (row>>1)&3
  #define STAGE(buf, src, c0)                                                   \
    { _Pragma("unroll")                                                         \
      for (int j = 0; j < 4; ++j) {                                             \
        const int row_ = srow + 16 * j;                                         \
        const int gi_  = sblk ^ ((row_ >> 1) & 3);                              \
        gload_lds16((src) + (size_t)row_ * 256 + (c0) + 8 * gi_,                \
                    &sStage[buf][wv * 2048 + j * 512]);                         \
      } }

  // Phase-2 staging: [32 d][256 q] chunk of Qt; LDS granule (row,gr) holds
  // global granule gr^(row&7). slot = (wv*4+j)*64 + lane; row=slot>>5, gr=slot&31.
  #define STAGE2(buf, cc)                                                       \
    { _Pragma("unroll")                                                         \
      for (int j = 0; j < 4; ++j) {                                             \
        const int slot_ = (wv * 4 + j) * 64 + lane;                             \
        const int row_  = slot_ >> 5;                                           \
        const int gr_   = slot_ & 31;                                           \
        gload_lds16(Qtb + (size_t)(32 * (cc) + row_) * 256 + 8 * (gr_ ^ (row_ & 7)), \
                    &sStage[buf][wv * 2048 + j * 512]);                         \
      } }

  float4v acc[16];
  #pragma unroll
  for (int n = 0; n < 16; ++n) acc[n] = (float4v)0.f;
  float s1part = 0.f;

  // ---- prologue ----
  float q2v[16];
  #pragma unroll
  for (int n = 0; n < 16; ++n) q2v[n] = q2_ws[b * NTQ + 16 * n + li];
  if (tid < 192) *(float4*)(sW + 4 * tid) = *(const float4*)(w + 4 * tid);
  STAGE(0, Qb, 0);
  const float* arow = ctxB + (size_t)(16 * wv + li) * ND + 8 * g;
  float4 Ac0 = *(const float4*)(arow);
  float4 Ac1 = *(const float4*)(arow + 4);
  asm volatile("s_waitcnt vmcnt(0) lgkmcnt(0)" ::: "memory");
  __builtin_amdgcn_s_barrier();
  __builtin_amdgcn_sched_barrier(0);

  const size_t gb0 = ((size_t)b * NTC + t0 + 16 * wv + li) * 1024 + 8 * g;

  // ---- Phase 1: chunks 0..7, counted-vmcnt two-barrier pipeline ----
  #pragma unroll
  for (int c = 0; c < 8; ++c) {
    float4 u0 = *(const float4*)(sW + 32 * c + 8 * g);
    float4 u1 = *(const float4*)(sW + 32 * c + 8 * g + 4);
    float4 v0 = *(const float4*)(sW + 512 + 32 * c + 8 * g);
    float4 v1 = *(const float4*)(sW + 512 + 32 * c + 8 * g + 4);
    s1part += Ac0.x*u0.x + Ac0.y*u0.y + Ac0.z*u0.z + Ac0.w*u0.w
            + Ac1.x*u1.x + Ac1.y*u1.y + Ac1.z*u1.z + Ac1.w*u1.w;
    short8v af;
    af[0]=f2bf(Ac0.x*v0.x); af[1]=f2bf(Ac0.y*v0.y); af[2]=f2bf(Ac0.z*v0.z); af[3]=f2bf(Ac0.w*v0.w);
    af[4]=f2bf(Ac1.x*v1.x); af[5]=f2bf(Ac1.y*v1.y); af[6]=f2bf(Ac1.z*v1.z); af[7]=f2bf(Ac1.w*v1.w);
    __builtin_amdgcn_sched_barrier(0);
    float4 An0, An1;
    if (c < 7) {
      An0 = *(const float4*)(arow + 32 * (c + 1));
      An1 = *(const float4*)(arow + 32 * (c + 1) + 4);
    }
    __builtin_amdgcn_sched_barrier(0);
    if (c < 7) { STAGE((c + 1) & 1, Qb, 32 * (c + 1)); }
    else       { STAGE2(0, 0); }               // phase-2 d-chunk 0 prefetch
    __builtin_amdgcn_sched_barrier(0);
    asm volatile("s_waitcnt vmcnt(6)" ::: "memory");   // chunk-c stage complete
    __builtin_amdgcn_s_barrier();
    __builtin_amdgcn_sched_barrier(0);
    const short* sb = sStage[c & 1];
    #pragma unroll
    for (int n = 0; n < 16; ++n) {
      const int row = 16 * n + li;
      short8v bb = *(const short8v*)(sb + row * 32 + 8 * (g ^ ((row >> 1) & 3)));
      acc[n] = __builtin_amdgcn_mfma_f32_16x16x32_bf16(af, bb, acc[n], 0, 0, 0);
    }
    *(float4*)(G + gb0 + 32 * c)     = Ac0;   // G0 = C (spread writes)
    *(float4*)(G + gb0 + 32 * c + 4) = Ac1;
    __builtin_amdgcn_sched_barrier(0);
    __builtin_amdgcn_s_barrier();             // readers done before next overwrite
    __builtin_amdgcn_sched_barrier(0);
    Ac0 = An0; Ac1 = An1;
  }

  // ---- softmax (rows 16wv+4g+r, cols 16n+li) ----
  s1part += __shfl_xor(s1part, 16);
  s1part += __shfl_xor(s1part, 32);
  float s1r[4];
  #pragma unroll
  for (int r = 0; r < 4; ++r) s1r[r] = __shfl(s1part, 4 * g + r);

  #pragma unroll
  for (int n = 0; n < 16; ++n)
    #pragma unroll
    for (int r = 0; r < 4; ++r) acc[n][r] += s1r[r] + q2v[n];

  float mx[4], inv[4];
  #pragma unroll
  for (int r = 0; r < 4; ++r) {
    float m0 = acc[0][r];
    #pragma unroll
    for (int n = 1; n < 16; ++n) m0 = fmaxf(m0, acc[n][r]);
    m0 = fmaxf(m0, __shfl_xor(m0, 1));
    m0 = fmaxf(m0, __shfl_xor(m0, 2));
    m0 = fmaxf(m0, __shfl_xor(m0, 4));
    m0 = fmaxf(m0, __shfl_xor(m0, 8));
    mx[r] = m0;
  }
  #pragma unroll
  for (int r = 0; r < 4; ++r) {
    float z = 0.f;
    #pragma unroll
    for (int n = 0; n < 16; ++n) { float e = __expf(acc[n][r] - mx[r]); acc[n][r] = e; z += e; }
    z += __shfl_xor(z, 1);
    z += __shfl_xor(z, 2);
    z += __shfl_xor(z, 4);
    z += __shfl_xor(z, 8);
    inv[r] = 1.0f / z;
  }
  #pragma unroll
  for (int n = 0; n < 16; ++n) {
    #pragma unroll
    for (int r = 0; r < 4; ++r)
      sPw[(4 * g + r) * PSTR + 16 * n + li] = f2bf(acc[n][r] * inv[r]);
  }

  // ---- tile b_t stats (pre-phase-2): Mloc, zloc, lane-local wgt ----
  float lm = fmaxf(fmaxf(mx[0], mx[1]), fmaxf(mx[2], mx[3]));
  lm = fmaxf(lm, __shfl_xor(lm, 16));
  lm = fmaxf(lm, __shfl_xor(lm, 32));
  if (lane == 0) sRedM[wv] = lm;
  __builtin_amdgcn_sched_barrier(0);
  asm volatile("s_waitcnt lgkmcnt(0)" ::: "memory");
  __builtin_amdgcn_s_barrier();
  __builtin_amdgcn_sched_barrier(0);
  const float Mloc = fmaxf(fmaxf(sRedM[0], sRedM[1]), fmaxf(sRedM[2], sRedM[3]));
  float wgt[4];
  float zp = 0.f;
  #pragma unroll
  for (int r = 0; r < 4; ++r) { wgt[r] = __expf(mx[r] - Mloc); zp += wgt[r]; }
  zp += __shfl_xor(zp, 16);
  zp += __shfl_xor(zp, 32);
  if (lane == 0) sRedZ[wv] = zp;

  // ---- Phase 2 (d-major): per 32-d chunk full-K accumulate, store inline ----
  #pragma unroll
  for (int cc = 0; cc < 8; ++cc) {
    if (cc < 7) { STAGE2((cc + 1) & 1, cc + 1); }
    __builtin_amdgcn_sched_barrier(0);
    if (cc < 7) asm volatile("s_waitcnt vmcnt(4)" ::: "memory");
    else        asm volatile("s_waitcnt vmcnt(0)" ::: "memory");
    __builtin_amdgcn_s_barrier();
    __builtin_amdgcn_sched_barrier(0);
    const short* sb = sStage[cc & 1];
    float4v uacc0 = (float4v)0.f, uacc1 = (float4v)0.f;
    #pragma unroll
    for (int ks = 0; ks < 8; ++ks) {
      short8v a2 = *(const short8v*)(sPw + li * PSTR + 32 * ks + 8 * g);
      short8v b0 = *(const short8v*)(sb + (li)      * 256 + 8 * ((4 * ks + g) ^ (li & 7)));
      short8v b1 = *(const short8v*)(sb + (16 + li) * 256 + 8 * ((4 * ks + g) ^ (li & 7)));
      uacc0 = __builtin_amdgcn_mfma_f32_16x16x32_bf16(a2, b0, uacc0, 0, 0, 0);
      uacc1 = __builtin_amdgcn_mfma_f32_16x16x32_bf16(a2, b1, uacc1, 0, 0, 0);
    }
    __builtin_amdgcn_sched_barrier(0);
    __builtin_amdgcn_s_barrier();             // all bb reads done before next STAGE2
    __builtin_amdgcn_sched_barrier(0);
    // stores + partial-h for this 32-d slice
    float hc0 = 0.f, hc1 = 0.f;
    #pragma unroll
    for (int r = 0; r < 4; ++r) {
      const int trow = 16 * wv + 4 * g + r;
      const size_t gb = ((size_t)b * NTC + t0 + trow) * 1024 + 32 * cc;
      const float* cp = ctxB + (size_t)trow * ND + 32 * cc;
      const float c0 = cp[li];
      const float c1 = cp[16 + li];
      const float uu0 = uacc0[r];
      const float uu1 = uacc1[r];
      G[gb + 256 + li]      = uu0;
      G[gb + 256 + 16 + li] = uu1;
      G[gb + 512 + li]      = c0 * uu0;
      G[gb + 512 + 16 + li] = c1 * uu1;
      hc0 += wgt[r] * c0;
      hc1 += wgt[r] * c1;
    }
    hc0 += __shfl_xor(hc0, 16); hc0 += __shfl_xor(hc0, 32);
    hc1 += __shfl_xor(hc1, 16); hc1 += __shfl_xor(hc1, 32);
    if (g == 0) {
      sHall[wv][32 * cc + li]      = hc0;
      sHall[wv][32 * cc + 16 + li] = hc1;
    }
  }

  // ---- final: combine per-wave partial h -> hp2 ----
  __syncthreads();
  float* hp = hp2 + (size_t)(b * 32 + tile) * 260;
  {
    const int d = tid & 255;
    float ph = sHall[0][d] + sHall[1][d] + sHall[2][d] + sHall[3][d];
    hp[d] = ph;
  }
  if (tid == 0) {
    hp[256] = Mloc;
    hp[257] = sRedZ[0] + sRedZ[1] + sRedZ[2] + sRedZ[3];
  }
  #undef STAGE
  #undef STAGE2
}

// K2h: per batch, combine 32 tile partials -> h[b][256]
__global__ __launch_bounds__(256) void k2h(const float* __restrict__ hp2,
                                           float* __restrict__ h_ws) {
  __shared__ float sM2[32], sZ2[32];
  const int b = blockIdx.x;
  const int tid = threadIdx.x;
  if (tid < 32) {
    sM2[tid] = hp2[(size_t)(b * 32 + tid) * 260 + 256];
    sZ2[tid] = hp2[(size_t)(b * 32 + tid) * 260 + 257];
  }
  __syncthreads();
  float M = -1e30f;
  #pragma unroll
  for (int i = 0; i < 32; ++i) M = fmaxf(M, sM2[i]);
  float Z = 0.f;
  float a = 0.f;
  #pragma unroll
  for (int i = 0; i < 32; ++i) {
    float e = __expf(sM2[i] - M);
    Z += sZ2[i] * e;
    a += hp2[(size_t)(b * 32 + i) * 260 + tid] * e;
  }
  h_ws[b * 256 + tid] = a / Z;
}

// K3: G[...,768:1024] = C * h[b,:]
__global__ __launch_bounds__(256) void k3_epi(const float* __restrict__ ctx,
                                              const float* __restrict__ h_ws,
                                              float* __restrict__ G) {
  size_t f = (size_t)blockIdx.x * 256 + threadIdx.x;
  size_t e = f * 4;
  int d = (int)(e & 255);
  size_t bt = e >> 8;
  int b = (int)(bt >> 11);
  float4 c = *(const float4*)(ctx + e);
  float4 h = *(const float4*)(h_ws + b * ND + d);
  *(float4*)(G + bt * 1024 + 768 + d) =
      make_float4(c.x * h.x, c.y * h.y, c.z * h.z, c.w * h.w);
}

extern "C" void kernel_launch(void* const* d_in, const int* in_sizes, int n_in,
                              void* d_out, int out_size, void* d_ws, size_t ws_size,
                              hipStream_t stream) {
  const float* ctx = (const float*)d_in[0];
  const float* qry = (const float*)d_in[1];
  const float* w   = (const float*)d_in[2];
  float* G  = (float*)d_out;
  float* ws = (float*)d_ws;
  float* hp2   = ws + HP2_OFF;
  float* h_ws  = ws + H_OFF;
  float* q2_ws = ws + Q2_OFF;
  short* Qbf = (short*)(ws + QBF_OFF);
  short* Qt  = (short*)(ws + QT_OFF);

  k0_prep<<<NB * 8, 256, 0, stream>>>(qry, w, q2_ws, Qbf, Qt);
  k1_main<<<NB * (NTC / 64), 256, 0, stream>>>(ctx, w, Qbf, Qt, q2_ws, hp2, G);
  k2h<<<NB, 256, 0, stream>>>(hp2, h_ws);
  k3_epi<<<16384, 256, 0, stream>>>(ctx, h_ws, G);
}

// Round 9
// 94.417 us; speedup vs baseline: 2.5899x; 1.0963x over previous
//
#include <hip/hip_runtime.h>

#define NB  32
#define NTC 2048
#define NTQ 256
#define ND  256

// ws layout (floats):
// hp2[32][32][260] @0 ; h[32][256] @266240 ; q2[32][256] @274432 ;
// Qbf(bf16) @282624f ; Qt(bf16) @+1M floats
#define HP2_OFF 0
#define H_OFF   266240
#define Q2_OFF  274432
#define QBF_OFF 282624
#define QT_OFF  (282624 + 1048576)

typedef __attribute__((ext_vector_type(8))) short short8v;
typedef __attribute__((ext_vector_type(4))) float float4v;
typedef unsigned int u32;

static __device__ inline short f2bf(float f) {
  union { float f; unsigned u; } v; v.f = f;
  unsigned r = v.u + 0x7FFFu + ((v.u >> 16) & 1u);
  return (short)(r >> 16);
}

static __device__ inline void gload_lds16(const short* g, short* l) {
  __builtin_amdgcn_global_load_lds(
      (const __attribute__((address_space(1))) u32*)g,
      (__attribute__((address_space(3))) u32*)l, 16, 0, 0);
}

// K0: per (b, 32-row q-chunk): Qbf = bf16(Q); Qt = bf16(Q)^T; q2 = Q.w2
__global__ __launch_bounds__(256) void k0_prep(const float* __restrict__ qry,
                                               const float* __restrict__ w,
                                               float* __restrict__ q2_ws,
                                               short* __restrict__ Qbf,
                                               short* __restrict__ Qt) {
  __shared__ float sRed[8][32];
  const int tid = threadIdx.x;
  const int b = blockIdx.x >> 3;
  const int q0 = (blockIdx.x & 7) << 5;
  const int q = tid & 31;
  const int dc = tid >> 5;
  const float* src = qry + (((size_t)b * NTQ) + q0 + q) * ND + dc * 32;
  const float* w2p = w + ND + dc * 32;

  float vals[32];
  float part = 0.f;
  #pragma unroll
  for (int i = 0; i < 8; ++i) {
    float4 v = *(const float4*)(src + 4 * i);
    float4 u = *(const float4*)(w2p + 4 * i);
    part += v.x*u.x + v.y*u.y + v.z*u.z + v.w*u.w;
    vals[4*i] = v.x; vals[4*i+1] = v.y; vals[4*i+2] = v.z; vals[4*i+3] = v.w;
  }
  short pk[32];
  #pragma unroll
  for (int i = 0; i < 32; ++i) pk[i] = f2bf(vals[i]);

  short* dst = Qbf + ((size_t)b * NTQ + q0 + q) * ND + dc * 32;
  #pragma unroll
  for (int i = 0; i < 4; ++i) *(short8v*)(dst + 8 * i) = *(short8v*)(pk + 8 * i);
  short* dstT = Qt + (size_t)b * NTQ * ND + q0 + q;
  #pragma unroll
  for (int i = 0; i < 32; ++i) dstT[(size_t)(dc * 32 + i) * NTQ] = pk[i];

  part += __shfl_xor(part, 32);
  if ((tid & 32) == 0) sRed[dc][q] = part;
  __syncthreads();
  if (tid < 32) {
    float s = sRed[0][tid] + sRed[2][tid] + sRed[4][tid] + sRed[6][tid];
    q2_ws[b * NTQ + q0 + tid] = s;
  }
}

// K1: per (b, 64-row tile). Swapped-operand phase 1 (acc = S^T, lane-owns-row),
// in-register P, shuffle-built phase-2 A-fragments. No sP LDS. 4 blocks/CU.
__global__ __launch_bounds__(256, 4) void k1_main(const float* __restrict__ ctx,
                                                  const float* __restrict__ w,
                                                  const short* __restrict__ Qbf,
                                                  const short* __restrict__ Qt,
                                                  const float* __restrict__ q2_ws,
                                                  float* __restrict__ hp2,
                                                  float* __restrict__ G) {
  __shared__ __align__(16) short sStage[2][256 * 32];    // 2 x 16KB
  __shared__ __align__(16) float sW[512];                // w1 | w3
  __shared__ __align__(16) float sQ2[256];               // q2 tile
  __shared__ __align__(16) float sHall[4][256];          // per-wave partial h
  __shared__ float sRedM[4], sRedZ[4];

  const int tid  = threadIdx.x;
  const int wv   = tid >> 6;
  const int lane = tid & 63;
  const int g    = lane >> 4;
  const int li   = lane & 15;
  const int bid  = blockIdx.x;
  const int obid = (bid & 7) * 128 + (bid >> 3);   // XCD-bijective swizzle
  const int b    = obid >> 5;
  const int tile = obid & 31;
  const int t0   = tile << 6;

  const float* __restrict__ ctxB = ctx + ((size_t)b * NTC + t0) * ND;
  const short* __restrict__ Qb   = Qbf + (size_t)b * NTQ * ND;
  const short* __restrict__ Qtb  = Qt  + (size_t)b * NTQ * ND;

  const int srow = 64 * wv + (lane >> 2);
  const int sblk = lane & 3;

  // Phase-1 staging: [256 q][32 k], granule swizzle (row>>1)&3
  #define STAGE(buf, src, c0)                                                   \
    { _Pragma("unroll")                                                         \
      for (int j = 0; j < 4; ++j) {                                             \
        const int row_ = srow + 16 * j;                                         \
        const int gi_  = sblk ^ ((row_ >> 1) & 3);                              \
        gload_lds16((src) + (size_t)row_ * 256 + (c0) + 8 * gi_,                \
                    &sStage[buf][wv * 2048 + j * 512]);                         \
      } }

  // Phase-2 staging: [32 d][256 q] of Qt; LDS granule (row,gr) = global gr^(row&7)
  #define STAGE2(buf, cc)                                                       \
    { _Pragma("unroll")                                                         \
      for (int j = 0; j < 4; ++j) {                                             \
        const int slot_ = (wv * 4 + j) * 64 + lane;                             \
        const int row_  = slot_ >> 5;                                           \
        const int gr_   = slot_ & 31;                                           \
        gload_lds16(Qtb + (size_t)(32 * (cc) + row_) * 256 + 8 * (gr_ ^ (row_ & 7)), \
                    &sStage[buf][wv * 2048 + j * 512]);                         \
      } }

  float4v acc[16];
  #pragma unroll
  for (int n = 0; n < 16; ++n) acc[n] = (float4v)0.f;
  float s1part = 0.f;

  // ---- prologue: w1/w3 + q2 -> LDS, stage chunk 0, A(0); full drain once ----
  if (tid < 64)       *(float4*)(sW + 4 * tid) = *(const float4*)(w + 4 * tid);
  else if (tid < 128) *(float4*)(sW + 4 * tid) = *(const float4*)(w + 512 + 4 * tid - 256);
  else if (tid < 192) *(float4*)(sQ2 + 4 * (tid - 128)) = *(const float4*)(q2_ws + b * NTQ + 4 * (tid - 128));
  STAGE(0, Qb, 0);
  const float* arow = ctxB + (size_t)(16 * wv + li) * ND + 8 * g;
  float4 Ac0 = *(const float4*)(arow);
  float4 Ac1 = *(const float4*)(arow + 4);
  asm volatile("s_waitcnt vmcnt(0) lgkmcnt(0)" ::: "memory");
  __builtin_amdgcn_s_barrier();
  __builtin_amdgcn_sched_barrier(0);

  const size_t gb0 = ((size_t)b * NTC + t0 + 16 * wv + li) * 1024 + 8 * g;

  // ---- Phase 1: chunks 0..7; acc[n][r] = S[t=16wv+li][q=16n+4g+r] ----
  #pragma unroll
  for (int c = 0; c < 8; ++c) {
    float4 u0 = *(const float4*)(sW + 32 * c + 8 * g);
    float4 u1 = *(const float4*)(sW + 32 * c + 8 * g + 4);
    float4 v0 = *(const float4*)(sW + 256 + 32 * c + 8 * g);
    float4 v1 = *(const float4*)(sW + 256 + 32 * c + 8 * g + 4);
    s1part += Ac0.x*u0.x + Ac0.y*u0.y + Ac0.z*u0.z + Ac0.w*u0.w
            + Ac1.x*u1.x + Ac1.y*u1.y + Ac1.z*u1.z + Ac1.w*u1.w;
    short8v af;
    af[0]=f2bf(Ac0.x*v0.x); af[1]=f2bf(Ac0.y*v0.y); af[2]=f2bf(Ac0.z*v0.z); af[3]=f2bf(Ac0.w*v0.w);
    af[4]=f2bf(Ac1.x*v1.x); af[5]=f2bf(Ac1.y*v1.y); af[6]=f2bf(Ac1.z*v1.z); af[7]=f2bf(Ac1.w*v1.w);
    __builtin_amdgcn_sched_barrier(0);
    float4 An0, An1;
    if (c < 7) {
      An0 = *(const float4*)(arow + 32 * (c + 1));
      An1 = *(const float4*)(arow + 32 * (c + 1) + 4);
    }
    __builtin_amdgcn_sched_barrier(0);
    if (c < 7) { STAGE((c + 1) & 1, Qb, 32 * (c + 1)); }
    else       { STAGE2(0, 0); }
    __builtin_amdgcn_sched_barrier(0);
    if (c == 7) asm volatile("s_waitcnt vmcnt(6)" ::: "memory");
    else        asm volatile("s_waitcnt vmcnt(8)" ::: "memory");
    __builtin_amdgcn_s_barrier();
    __builtin_amdgcn_sched_barrier(0);
    const short* sb = sStage[c & 1];
    #pragma unroll
    for (int n = 0; n < 16; ++n) {
      const int row = 16 * n + li;
      short8v bb = *(const short8v*)(sb + row * 32 + 8 * (g ^ ((row >> 1) & 3)));
      acc[n] = __builtin_amdgcn_mfma_f32_16x16x32_bf16(bb, af, acc[n], 0, 0, 0);  // SWAPPED
    }
    *(float4*)(G + gb0 + 32 * c)     = Ac0;   // G0 = C
    *(float4*)(G + gb0 + 32 * c + 4) = Ac1;
    __builtin_amdgcn_sched_barrier(0);
    __builtin_amdgcn_s_barrier();
    __builtin_amdgcn_sched_barrier(0);
    Ac0 = An0; Ac1 = An1;
  }

  // ---- softmax: lane owns row t = 16wv+li, q spread over (n, r) per g ----
  s1part += __shfl_xor(s1part, 16);
  s1part += __shfl_xor(s1part, 32);
  #pragma unroll
  for (int n = 0; n < 16; ++n) {
    float4 qv = *(const float4*)(sQ2 + 16 * n + 4 * g);
    acc[n][0] += s1part + qv.x;
    acc[n][1] += s1part + qv.y;
    acc[n][2] += s1part + qv.z;
    acc[n][3] += s1part + qv.w;
  }
  float mx = acc[0][0];
  #pragma unroll
  for (int n = 0; n < 16; ++n)
    #pragma unroll
    for (int r = 0; r < 4; ++r) mx = fmaxf(mx, acc[n][r]);
  mx = fmaxf(mx, __shfl_xor(mx, 16));
  mx = fmaxf(mx, __shfl_xor(mx, 32));
  float z = 0.f;
  #pragma unroll
  for (int n = 0; n < 16; ++n)
    #pragma unroll
    for (int r = 0; r < 4; ++r) { float e = __expf(acc[n][r] - mx); acc[n][r] = e; z += e; }
  z += __shfl_xor(z, 16);
  z += __shfl_xor(z, 32);
  const float inv = 1.0f / z;

  // ---- tile b_t stats: Mloc over 16 t (and 4 waves), zloc, weights ----
  float tm = mx;
  tm = fmaxf(tm, __shfl_xor(tm, 1));
  tm = fmaxf(tm, __shfl_xor(tm, 2));
  tm = fmaxf(tm, __shfl_xor(tm, 4));
  tm = fmaxf(tm, __shfl_xor(tm, 8));
  if (lane == 0) sRedM[wv] = tm;
  __builtin_amdgcn_sched_barrier(0);
  asm volatile("s_waitcnt lgkmcnt(0)" ::: "memory");
  __builtin_amdgcn_s_barrier();
  __builtin_amdgcn_sched_barrier(0);
  const float Mloc = fmaxf(fmaxf(sRedM[0], sRedM[1]), fmaxf(sRedM[2], sRedM[3]));
  const float wgt = __expf(mx - Mloc);     // weight of own t-row
  float zp = wgt;
  zp += __shfl_xor(zp, 1);
  zp += __shfl_xor(zp, 2);
  zp += __shfl_xor(zp, 4);
  zp += __shfl_xor(zp, 8);
  if (lane == 0) sRedZ[wv] = zp;
  float wgtRow[4];
  #pragma unroll
  for (int r = 0; r < 4; ++r) wgtRow[r] = __shfl(wgt, 4 * g + r);

  // ---- pack P to bf16 dwords; build phase-2 A-fragments by cross-g shuffle ----
  int pkx[16], pky[16];
  #pragma unroll
  for (int n = 0; n < 16; ++n) {
    pkx[n] = (int)(u32)(unsigned short)f2bf(acc[n][0] * inv)
           | ((int)(u32)(unsigned short)f2bf(acc[n][1] * inv) << 16);
    pky[n] = (int)(u32)(unsigned short)f2bf(acc[n][2] * inv)
           | ((int)(u32)(unsigned short)f2bf(acc[n][3] * inv) << 16);
  }
  const int srcLow  = ((g & 1) << 5) + li;
  const int srcHigh = srcLow + 16;
  const bool hiSel  = (g >= 2);
  short8v a2f[8];
  #pragma unroll
  for (int ks = 0; ks < 8; ++ks) {
    int eL0 = __shfl(pkx[2 * ks],     srcLow);
    int eL1 = __shfl(pky[2 * ks],     srcLow);
    int oL0 = __shfl(pkx[2 * ks + 1], srcLow);
    int oL1 = __shfl(pky[2 * ks + 1], srcLow);
    int eH0 = __shfl(pkx[2 * ks],     srcHigh);
    int eH1 = __shfl(pky[2 * ks],     srcHigh);
    int oH0 = __shfl(pkx[2 * ks + 1], srcHigh);
    int oH1 = __shfl(pky[2 * ks + 1], srcHigh);
    union { int i[4]; short8v s; } u;
    u.i[0] = hiSel ? oL0 : eL0;
    u.i[1] = hiSel ? oL1 : eL1;
    u.i[2] = hiSel ? oH0 : eH0;
    u.i[3] = hiSel ? oH1 : eH1;
    a2f[ks] = u.s;
  }

  // ---- Phase 2 (d-major): per 32-d chunk full-K U = P Q, stores inline ----
  #pragma unroll
  for (int cc = 0; cc < 8; ++cc) {
    if (cc < 7) { STAGE2((cc + 1) & 1, cc + 1); }
    __builtin_amdgcn_sched_barrier(0);
    if (cc == 0)      asm volatile("s_waitcnt vmcnt(6)"  ::: "memory");
    else if (cc == 7) asm volatile("s_waitcnt vmcnt(24)" ::: "memory");
    else              asm volatile("s_waitcnt vmcnt(28)" ::: "memory");
    __builtin_amdgcn_s_barrier();
    __builtin_amdgcn_sched_barrier(0);
    const short* sb = sStage[cc & 1];
    float4v uacc0 = (float4v)0.f, uacc1 = (float4v)0.f;
    #pragma unroll
    for (int ks = 0; ks < 8; ++ks) {
      short8v b0 = *(const short8v*)(sb + (li)      * 256 + 8 * ((4 * ks + g) ^ (li & 7)));
      short8v b1 = *(const short8v*)(sb + (16 + li) * 256 + 8 * ((4 * ks + g) ^ (li & 7)));
      uacc0 = __builtin_amdgcn_mfma_f32_16x16x32_bf16(a2f[ks], b0, uacc0, 0, 0, 0);
      uacc1 = __builtin_amdgcn_mfma_f32_16x16x32_bf16(a2f[ks], b1, uacc1, 0, 0, 0);
    }
    __builtin_amdgcn_sched_barrier(0);
    __builtin_amdgcn_s_barrier();
    __builtin_amdgcn_sched_barrier(0);
    float hc0 = 0.f, hc1 = 0.f;
    #pragma unroll
    for (int r = 0; r < 4; ++r) {
      const int trow = 16 * wv + 4 * g + r;
      const size_t gb = ((size_t)b * NTC + t0 + trow) * 1024 + 32 * cc;
      const float* cp = ctxB + (size_t)trow * ND + 32 * cc;
      const float c0 = cp[li];
      const float c1 = cp[16 + li];
      const float uu0 = uacc0[r];
      const float uu1 = uacc1[r];
      G[gb + 256 + li]      = uu0;
      G[gb + 256 + 16 + li] = uu1;
      G[gb + 512 + li]      = c0 * uu0;
      G[gb + 512 + 16 + li] = c1 * uu1;
      hc0 += wgtRow[r] * c0;
      hc1 += wgtRow[r] * c1;
    }
    hc0 += __shfl_xor(hc0, 16); hc0 += __shfl_xor(hc0, 32);
    hc1 += __shfl_xor(hc1, 16); hc1 += __shfl_xor(hc1, 32);
    if (g == 0) {
      sHall[wv][32 * cc + li]      = hc0;
      sHall[wv][32 * cc + 16 + li] = hc1;
    }
  }

  // ---- final: combine per-wave partial h -> hp2 ----
  __syncthreads();
  float* hp = hp2 + (size_t)(b * 32 + tile) * 260;
  {
    const int d = tid & 255;
    float ph = sHall[0][d] + sHall[1][d] + sHall[2][d] + sHall[3][d];
    hp[d] = ph;
  }
  if (tid == 0) {
    hp[256] = Mloc;
    hp[257] = sRedZ[0] + sRedZ[1] + sRedZ[2] + sRedZ[3];
  }
  #undef STAGE
  #undef STAGE2
}

// K2h: per batch, combine 32 tile partials -> h[b][256]
__global__ __launch_bounds__(256) void k2h(const float* __restrict__ hp2,
                                           float* __restrict__ h_ws) {
  __shared__ float sM2[32], sZ2[32];
  const int b = blockIdx.x;
  const int tid = threadIdx.x;
  if (tid < 32) {
    sM2[tid] = hp2[(size_t)(b * 32 + tid) * 260 + 256];
    sZ2[tid] = hp2[(size_t)(b * 32 + tid) * 260 + 257];
  }
  __syncthreads();
  float M = -1e30f;
  #pragma unroll
  for (int i = 0; i < 32; ++i) M = fmaxf(M, sM2[i]);
  float Z = 0.f;
  float a = 0.f;
  #pragma unroll
  for (int i = 0; i < 32; ++i) {
    float e = __expf(sM2[i] - M);
    Z += sZ2[i] * e;
    a += hp2[(size_t)(b * 32 + i) * 260 + tid] * e;
  }
  h_ws[b * 256 + tid] = a / Z;
}

// K3: G[...,768:1024] = C * h[b,:]
__global__ __launch_bounds__(256) void k3_epi(const float* __restrict__ ctx,
                                              const float* __restrict__ h_ws,
                                              float* __restrict__ G) {
  size_t f = (size_t)blockIdx.x * 256 + threadIdx.x;
  size_t e = f * 4;
  int d = (int)(e & 255);
  size_t bt = e >> 8;
  int b = (int)(bt >> 11);
  float4 c = *(const float4*)(ctx + e);
  float4 h = *(const float4*)(h_ws + b * ND + d);
  *(float4*)(G + bt * 1024 + 768 + d) =
      make_float4(c.x * h.x, c.y * h.y, c.z * h.z, c.w * h.w);
}

extern "C" void kernel_launch(void* const* d_in, const int* in_sizes, int n_in,
                              void* d_out, int out_size, void* d_ws, size_t ws_size,
                              hipStream_t stream) {
  const float* ctx = (const float*)d_in[0];
  const float* qry = (const float*)d_in[1];
  const float* w   = (const float*)d_in[2];
  float* G  = (float*)d_out;
  float* ws = (float*)d_ws;
  float* hp2   = ws + HP2_OFF;
  float* h_ws  = ws + H_OFF;
  float* q2_ws = ws + Q2_OFF;
  short* Qbf = (short*)(ws + QBF_OFF);
  short* Qt  = (short*)(ws + QT_OFF);

  k0_prep<<<NB * 8, 256, 0, stream>>>(qry, w, q2_ws, Qbf, Qt);
  k1_main<<<NB * (NTC / 64), 256, 0, stream>>>(ctx, w, Qbf, Qt, q2_ws, hp2, G);
  k2h<<<NB, 256, 0, stream>>>(hp2, h_ws);
  k3_epi<<<16384, 256, 0, stream>>>(ctx, h_ws, G);
}